// Round 6
// baseline (327.337 us; speedup 1.0000x reference)
//
#include <hip/hip_runtime.h>

typedef unsigned short u16;
typedef __attribute__((ext_vector_type(4))) float f4;
typedef __attribute__((ext_vector_type(8))) short bf8;
typedef __attribute__((ext_vector_type(4))) unsigned short u16x4;

#define B_ 8
#define C_ 512
#define T_ 2048
#define S_ 2048
#define SCALE_W 0.70710678118654752440f

__device__ __forceinline__ u16 f2bf(float f) {
  unsigned u = __builtin_bit_cast(unsigned, f);
  unsigned r = 0x7FFFu + ((u >> 16) & 1u);
  return (u16)((u + r) >> 16);
}
__device__ __forceinline__ float bf2f(u16 h) {
  unsigned u = ((unsigned)h) << 16;
  return __builtin_bit_cast(float, u);
}

__device__ __forceinline__ void gload16(const u16* g, u16* l) {
  __builtin_amdgcn_global_load_lds((__attribute__((address_space(1))) const void*)g,
                                   (__attribute__((address_space(3))) void*)l, 16, 0, 0);
}

#define MEMF() asm volatile("" ::: "memory")
#define BAR()  do { MEMF(); __builtin_amdgcn_s_barrier(); MEMF(); } while (0)
#define LGKM0() do { asm volatile("s_waitcnt lgkmcnt(0)" ::: "memory"); \
                     __builtin_amdgcn_sched_barrier(0); } while (0)

// ---------- prep: transpose [B,C,X] -> [B,X,C], split to bf16 hi/lo
__global__ __launch_bounds__(256) void transpose_kernel(
    const float* __restrict__ in, u16* __restrict__ oh, u16* __restrict__ ol, int X)
{
  __shared__ float t[32][33];
  const int tx = threadIdx.x, ty = threadIdx.y;
  const long cbase = (long)blockIdx.z * C_ + blockIdx.y * 32;
  const long xbase = (long)blockIdx.x * 32;
  const float* ip = in + cbase * X + xbase;
#pragma unroll
  for (int i = 0; i < 4; ++i)
    t[ty + i * 8][tx] = ip[(long)(ty + i * 8) * X + tx];
  __syncthreads();
  const long obase = ((long)blockIdx.z * X + xbase) * C_ + blockIdx.y * 32;
#pragma unroll
  for (int i = 0; i < 4; ++i) {
    float v = t[tx][ty + i * 8];
    long idx = obase + (long)(ty + i * 8) * C_ + tx;
    u16 h = f2bf(v);
    oh[idx] = h;
    ol[idx] = f2bf(v - bf2f(h));
  }
}

// ---------- prep: elementwise split f32 -> bf16 hi (and optional lo)
__global__ __launch_bounds__(256) void split_kernel(
    const float* __restrict__ in, u16* __restrict__ oh, u16* __restrict__ ol, long n4)
{
  long i = (long)blockIdx.x * 256 + threadIdx.x;
  const long stride = (long)gridDim.x * 256;
  for (; i < n4; i += stride) {
    f4 v = ((const f4*)in)[i];
    u16x4 hv, lv;
#pragma unroll
    for (int j = 0; j < 4; ++j) {
      u16 h = f2bf(v[j]);
      hv[j] = h;
      lv[j] = f2bf(v[j] - bf2f(h));
    }
    ((u16x4*)oh)[i] = hv;
    if (ol) ((u16x4*)ol)[i] = lv;
  }
}

// ---------- old-structure GEMM (128x128, BK=32): out[M][N] = A[M][K] * B[N][K]^T
// NPASS=3: hi/lo 3-pass. EPI=1: +base(original [B,C,T] layout)+bias, *SCALE, hi/lo store.
template<int NPASS, int EPI>
__global__ __launch_bounds__(256, 2) void gemm_kernel(
    const u16* __restrict__ Ah, const u16* __restrict__ Al,
    const u16* __restrict__ Bh, const u16* __restrict__ Bl,
    int M, int N, int K,
    long sA, long sB, long sO,
    const float* __restrict__ baseO, const float* __restrict__ bias,
    u16* __restrict__ outH, u16* __restrict__ outL,
    float* __restrict__ outF)
{
  constexpr int BM = 128, BK = 32;
  constexpr int TILE = BM * BK;
  __shared__ u16 lA[(NPASS == 3 ? 2 : 1) * TILE];
  __shared__ u16 lB[(NPASS == 3 ? 2 : 1) * TILE];
  u16* lAh = lA; u16* lAl = (NPASS == 3) ? (lA + TILE) : lA;
  u16* lBh = lB; u16* lBl = (NPASS == 3) ? (lB + TILE) : lB;

  const int tid = threadIdx.x;
  const int wid = tid >> 6;
  const int lane = tid & 63;
  const int wr = wid >> 1, wc = wid & 1;
  const int bz = blockIdx.z;
  const int m0 = blockIdx.y * BM;
  const int n0 = blockIdx.x * BM;

  const u16* gAh = Ah + (long)bz * sA + (long)m0 * K;
  const u16* gAl = (NPASS == 3) ? (Al + (long)bz * sA + (long)m0 * K) : nullptr;
  const u16* gBh = Bh + (long)bz * sB + (long)n0 * K;
  const u16* gBl = (NPASS == 3) ? (Bl + (long)bz * sB + (long)n0 * K) : nullptr;

  const int srow = tid >> 2;
  const int skoff = (tid & 3) * 8;
  const int ldsOff = wid * 512;

  f4 acc[4][4] = {};

  for (int k0 = 0; k0 < K; k0 += BK) {
    __syncthreads();
#pragma unroll
    for (int c = 0; c < 2; ++c) {
      const long go = (long)(c * 64 + srow) * K + k0 + skoff;
      const int lo = c * 2048 + ldsOff;
      gload16(gAh + go, lAh + lo);
      if (NPASS == 3) gload16(gAl + go, lAl + lo);
      gload16(gBh + go, lBh + lo);
      if (NPASS == 3) gload16(gBl + go, lBl + lo);
    }
    asm volatile("s_waitcnt vmcnt(0)" ::: "memory");
    __syncthreads();

    bf8 a_h[4], b_h[4], a_l[4], b_l[4];
    const int fr = lane & 15;
    const int fk = (lane >> 4) * 8;
#pragma unroll
    for (int i = 0; i < 4; ++i) {
      a_h[i] = *(const bf8*)&lAh[(wr * 64 + i * 16 + fr) * BK + fk];
      b_h[i] = *(const bf8*)&lBh[(wc * 64 + i * 16 + fr) * BK + fk];
      if (NPASS == 3) {
        a_l[i] = *(const bf8*)&lAl[(wr * 64 + i * 16 + fr) * BK + fk];
        b_l[i] = *(const bf8*)&lBl[(wc * 64 + i * 16 + fr) * BK + fk];
      }
    }
#pragma unroll
    for (int mi = 0; mi < 4; ++mi)
#pragma unroll
      for (int ni = 0; ni < 4; ++ni) {
        acc[mi][ni] = __builtin_amdgcn_mfma_f32_16x16x32_bf16(a_h[mi], b_h[ni], acc[mi][ni], 0, 0, 0);
        if (NPASS == 3) {
          acc[mi][ni] = __builtin_amdgcn_mfma_f32_16x16x32_bf16(a_h[mi], b_l[ni], acc[mi][ni], 0, 0, 0);
          acc[mi][ni] = __builtin_amdgcn_mfma_f32_16x16x32_bf16(a_l[mi], b_h[ni], acc[mi][ni], 0, 0, 0);
        }
      }
  }

  const int fr = lane & 15;
  const int r4 = (lane >> 4) * 4;
#pragma unroll
  for (int mi = 0; mi < 4; ++mi) {
#pragma unroll
    for (int ni = 0; ni < 4; ++ni) {
      const int gn = n0 + wc * 64 + ni * 16 + fr;
      const long gmb = m0 + wr * 64 + mi * 16 + r4;
      if (EPI == 1) {
        // base in original [B][C][T] layout: channel gn, t = gmb..gmb+3 (f4 aligned)
        f4 bv = *(const f4*)(baseO + ((long)bz * C_ + gn) * T_ + gmb);
        const float bs = bias[gn];
#pragma unroll
        for (int r = 0; r < 4; ++r) {
          float val = (acc[mi][ni][r] + bv[r] + bs) * SCALE_W;
          const long idx = (long)bz * sO + (gmb + r) * (long)N + gn;
          u16 h = f2bf(val);
          outH[idx] = h;
          outL[idx] = f2bf(val - bf2f(h));
        }
      } else {
#pragma unroll
        for (int r = 0; r < 4; ++r)
          outF[(long)bz * sO + (gmb + r) * (long)N + gn] = acc[mi][ni][r];
      }
    }
  }
}

// ---------- 256x256 / BK=64 / 8-wave phase-pipelined GEMM (counted vmcnt)
// LDS swizzle: byte_col ^= (row&1)<<6 within each 128B row — spreads a wave's
// ds_read_b128 across all 32 banks (even fr -> one 64B window, odd fr -> other).
// Computes pre_a[t][s] = Ah.Bh + Ah.Bl + Al.Bh over K=512 via 24 k-tiles of 64:
// tiles 0-7: Ah x Bh; 8-15: Ah x Bl; 16-23: Al x Bh. All operands K-contiguous, stride C_.
__device__ __forceinline__ void stage2(const u16* g, u16* l) {
  gload16(g, l);
  gload16(g + 64 * C_, l + 4096);
}
template<int NF>
__device__ __forceinline__ void rd_frags(bf8 (&d)[NF][2], const u16* p, int k0o, int k1o) {
#pragma unroll
  for (int i = 0; i < NF; ++i) {
    d[i][0] = *(const bf8*)&p[i * 1024 + k0o];
    d[i][1] = *(const bf8*)&p[i * 1024 + k1o];
  }
}
template<int MH, int NH>
__device__ __forceinline__ void mmq(f4 (&acc)[8][4], const bf8 (&a)[4][2], const bf8 (&b)[2][2]) {
  __builtin_amdgcn_s_setprio(1);
#pragma unroll
  for (int mi = 0; mi < 4; ++mi)
#pragma unroll
    for (int ni = 0; ni < 2; ++ni)
#pragma unroll
      for (int ks = 0; ks < 2; ++ks)
        acc[MH * 4 + mi][NH * 2 + ni] = __builtin_amdgcn_mfma_f32_16x16x32_bf16(
            a[mi][ks], b[ni][ks], acc[MH * 4 + mi][NH * 2 + ni], 0, 0, 0);
  __builtin_amdgcn_s_setprio(0);
}

__global__ __launch_bounds__(512, 2) void gemm8p_kernel(
    const u16* __restrict__ Ah, const u16* __restrict__ Al,
    const u16* __restrict__ Bh, const u16* __restrict__ Bl,
    float* __restrict__ outF)
{
  __shared__ u16 lds[65536];  // A: [2buf][256r][64c] @0 ; B: same @32768 (u16 units)
  const int tid = threadIdx.x;
  const int wid = tid >> 6, lane = tid & 63;
  const int wr = wid >> 2, wc = wid & 3;

  // bijective XCD swizzle (nwg = 512, divisible by 8)
  const int gx = gridDim.x, gy = gridDim.y;
  int lin = blockIdx.x + gx * (blockIdx.y + gy * blockIdx.z);
  const int nwg = gx * gy * (int)gridDim.z;
  lin = (lin & 7) * (nwg >> 3) + (lin >> 3);
  const int bx = lin % gx;
  const int tmp = lin / gx;
  const int by = tmp % gy, bz = tmp / gy;

  const int m0 = by * 256, n0 = bx * 256;
  const u16* gAh = Ah + ((long)bz * T_ + m0) * C_;
  const u16* gAl = Al + ((long)bz * T_ + m0) * C_;
  const u16* gBh = Bh + ((long)bz * S_ + n0) * C_;
  const u16* gBl = Bl + ((long)bz * S_ + n0) * C_;

  // staging geometry: per half-tile (128 rows x 64 cols u16), 2 gloads/thread.
  // LDS dest linear; source col carries the inverse swizzle (row&1 XOR on byte bit 6).
  const int srow = tid >> 3;                                         // 0..63
  const int scol = (((tid & 7) * 16) ^ ((srow & 1) << 6)) >> 1;      // u16
  const int dstA = tid * 8;                                          // u16

  // fragment-read geometry: nominal u16 col = ks*32 + (lane>>4)*8, row parity e=fr&1
  // swizzled u16 col = ((ks^e)*32) + (lane>>4)*8
  const int fr = lane & 15;
  const int e  = fr & 1;
  const int cb = (lane >> 4) * 8;
  const int k0o = e * 32;
  const int k1o = 32 - k0o;
  const int abase = (wr * 128 + fr) * 64 + cb;
  const int bbase = 32768 + (wc * 64 + fr) * 64 + cb;

  f4 acc[8][4] = {};
  constexpr int NT = 24;

#define SRC_A(tt) ((((tt) >> 3) == 2 ? gAl : gAh) + ((tt) & 7) * 64)
#define SRC_B(tt) ((((tt) >> 3) == 1 ? gBl : gBh) + ((tt) & 7) * 64)
#define STAGE_A(tt, h) stage2(SRC_A(tt) + (long)((h) * 128 + srow) * C_ + scol, \
                              lds + (((tt) & 1) * 16384 + (h) * 8192 + dstA))
#define STAGE_B(tt, h) stage2(SRC_B(tt) + (long)((h) * 128 + srow) * C_ + scol, \
                              lds + (32768 + ((tt) & 1) * 16384 + (h) * 8192 + dstA))

  // prologue: tile0 fully + B(1,0) (10 loads in flight)
  STAGE_B(0, 0); STAGE_B(0, 1); STAGE_A(0, 0); STAGE_A(0, 1); STAGE_B(1, 0);
  asm volatile("s_waitcnt vmcnt(2)" ::: "memory");  // tile0 landed; B(1)h0 may fly
  BAR();

  bf8 af[4][2], b0[2][2], b1[2][2];
  for (int kt = 0; kt < NT - 1; ++kt) {
    const int cur = kt & 1;
    const u16* la = lds + cur * 16384 + abase;
    const u16* lb = lds + cur * 16384 + bbase;
    // ---- ph1: Q(0,0)
    rd_frags(af, la, k0o, k1o);
    rd_frags(b0, lb, k0o, k1o);
    STAGE_B(kt + 1, 1);
    BAR(); LGKM0();
    mmq<0, 0>(acc, af, b0);
    BAR();
    // ---- ph2: Q(0,1)
    rd_frags(b1, lb + 2048, k0o, k1o);
    STAGE_A(kt + 1, 0);
    BAR(); LGKM0();
    mmq<0, 1>(acc, af, b1);
    BAR();
    // ---- ph3: Q(1,0)
    rd_frags(af, la + 4096, k0o, k1o);
    STAGE_A(kt + 1, 1);
    BAR(); LGKM0();
    mmq<1, 0>(acc, af, b0);
    BAR();
    // ---- ph4: Q(1,1)
    {
      int t2 = kt + 2; if (t2 > NT - 1) t2 = NT - 1;  // harmless duplicate re-stage at tail
      STAGE_B(t2, 0);
    }
    BAR();
    mmq<1, 1>(acc, af, b1);
    if (kt == NT - 2) { asm volatile("s_waitcnt vmcnt(0)" ::: "memory"); }
    else             { asm volatile("s_waitcnt vmcnt(2)" ::: "memory"); }
    BAR();
  }
  // peeled final tile (no staging)
  {
    const int cur = (NT - 1) & 1;
    const u16* la = lds + cur * 16384 + abase;
    const u16* lb = lds + cur * 16384 + bbase;
    rd_frags(af, la, k0o, k1o);
    rd_frags(b0, lb, k0o, k1o);
    BAR(); LGKM0();
    mmq<0, 0>(acc, af, b0);
    BAR();
    rd_frags(b1, lb + 2048, k0o, k1o);
    BAR(); LGKM0();
    mmq<0, 1>(acc, af, b1);
    BAR();
    rd_frags(af, la + 4096, k0o, k1o);
    BAR(); LGKM0();
    mmq<1, 0>(acc, af, b0);
    BAR();
    mmq<1, 1>(acc, af, b1);
  }
#undef SRC_A
#undef SRC_B
#undef STAGE_A
#undef STAGE_B

  // epilogue: f32 C-write to attn [T][S]
  const int r4 = (lane >> 4) * 4;
#pragma unroll
  for (int am = 0; am < 8; ++am) {
#pragma unroll
    for (int an = 0; an < 4; ++an) {
      const long gm = m0 + wr * 128 + am * 16 + r4;
      const int gn = n0 + wc * 64 + an * 16 + fr;
      float* po = outF + (long)bz * T_ * S_ + gm * (long)S_ + gn;
#pragma unroll
      for (int r = 0; r < 4; ++r) po[(long)r * S_] = acc[am][an][r];
    }
  }
}

// ---------- softmax over last dim (rows of 2048 f32), in place + bf16 copy out
__global__ __launch_bounds__(256) void softmax_kernel(float* __restrict__ a,
                                                      u16* __restrict__ ab) {
  const int tid = threadIdx.x;
  float* p = a + (long)blockIdx.x * 2048;
  u16* pb = ab + (long)blockIdx.x * 2048;
  f4 v0 = ((const f4*)p)[tid];
  f4 v1 = ((const f4*)p)[tid + 256];
  float m = fmaxf(fmaxf(fmaxf(v0[0], v0[1]), fmaxf(v0[2], v0[3])),
                  fmaxf(fmaxf(v1[0], v1[1]), fmaxf(v1[2], v1[3])));
#pragma unroll
  for (int o = 32; o >= 1; o >>= 1) m = fmaxf(m, __shfl_xor(m, o));
  __shared__ float redm[4], reds[4];
  if ((tid & 63) == 0) redm[tid >> 6] = m;
  __syncthreads();
  m = fmaxf(fmaxf(redm[0], redm[1]), fmaxf(redm[2], redm[3]));
  float s = 0.f;
#pragma unroll
  for (int j = 0; j < 4; ++j) { v0[j] = __expf(v0[j] - m); s += v0[j]; }
#pragma unroll
  for (int j = 0; j < 4; ++j) { v1[j] = __expf(v1[j] - m); s += v1[j]; }
#pragma unroll
  for (int o = 32; o >= 1; o >>= 1) s += __shfl_xor(s, o);
  if ((tid & 63) == 0) reds[tid >> 6] = s;
  __syncthreads();
  const float inv = 1.0f / (reds[0] + reds[1] + reds[2] + reds[3]);
  v0 *= inv; v1 *= inv;
  ((f4*)p)[tid] = v0;
  ((f4*)p)[tid + 256] = v1;
  u16x4 c0, c1;
#pragma unroll
  for (int j = 0; j < 4; ++j) { c0[j] = f2bf(v0[j]); c1[j] = f2bf(v1[j]); }
  ((u16x4*)pb)[tid] = c0;
  ((u16x4*)pb)[tid + 256] = c1;
}

extern "C" void kernel_launch(void* const* d_in, const int* in_sizes, int n_in,
                              void* d_out, int out_size, void* d_ws, size_t ws_size,
                              hipStream_t stream) {
  const float* base  = (const float*)d_in[0];
  const float* x     = (const float*)d_in[1];
  const float* enc_t = (const float*)d_in[2];
  const float* enc_c = (const float*)d_in[3];
  const float* W     = (const float*)d_in[4];
  const float* bias  = (const float*)d_in[5];

  float* ctx  = (float*)d_out;                       // [B,C,T]
  float* attn = ctx + (long)B_ * C_ * T_;            // [B,T,S]

  const long NBTC = (long)B_ * T_ * C_;              // 8388608
  u16* x_hi  = (u16*)d_ws;
  u16* x_lo  = x_hi + NBTC;
  u16* et_hi = x_lo + NBTC;
  u16* et_lo = et_hi + NBTC;
  u16* ec_hi = et_lo + NBTC;
  u16* w_hi  = ec_hi + NBTC;
  u16* w_lo  = w_hi + (long)C_ * C_;

  // target hi/lo splits in d_out ctx region (2*NBTC u16 = exactly 32 MB, dead until GEMM3)
  u16* t_hi = (u16*)d_out;
  u16* t_lo = t_hi + NBTC;
  // attn bf16 copy aliases x_hi..et_lo (exactly 4*NBTC u16 = B*T*S), all dead after GEMM2
  u16* attn_bf = x_hi;

  dim3 tb(32, 8);
  // x [B,C,T] -> x_hi/x_lo [B,T,C]
  transpose_kernel<<<dim3(T_ / 32, C_ / 32, B_), tb, 0, stream>>>(x, x_hi, x_lo, T_);
  // enc_t [B,C,S] -> et_hi/et_lo [B,S,C]
  transpose_kernel<<<dim3(S_ / 32, C_ / 32, B_), tb, 0, stream>>>(enc_t, et_hi, et_lo, S_);
  // enc_c -> ec_hi bf16 (no transpose, hi only)
  split_kernel<<<2048, 256, 0, stream>>>(enc_c, ec_hi, nullptr, (long)B_ * C_ * S_ / 4);
  // W -> w_hi/w_lo
  split_kernel<<<256, 256, 0, stream>>>(W, w_hi, w_lo, (long)C_ * C_ / 4);

  // GEMM1 (old structure, 3-pass): target^T[t][o] = sum_c x^T[t][c]*W[o][c];
  // epilogue +base(original layout)+bias, *scale, hi/lo store
  gemm_kernel<3, 1><<<dim3(C_ / 128, T_ / 128, B_), 256, 0, stream>>>(
      x_hi, x_lo, w_hi, w_lo,
      T_, C_, C_, (long)T_ * C_, 0L, (long)T_ * C_,
      base, bias, t_hi, t_lo, nullptr);

  // GEMM2 (256x256 8-phase, 24 k-tiles with hi/lo pointer switching) -> attn f32
  gemm8p_kernel<<<dim3(S_ / 256, T_ / 256, B_), 512, 0, stream>>>(
      t_hi, t_lo, et_hi, et_lo, attn);

  // softmax rows in place + bf16 copy
  softmax_kernel<<<B_ * T_, 256, 0, stream>>>(attn, attn_bf);

  // GEMM3 (old structure, 1-pass): ctx[c][t] = sum_s ec[c][s] * attn_bf[t][s]
  // grid: N=T_ -> x, M=C_ -> y (C_/128 = 4 blocks), B_ -> z
  gemm_kernel<1, 0><<<dim3(T_ / 128, C_ / 128, B_), 256, 0, stream>>>(
      ec_hi, nullptr, attn_bf, nullptr,
      C_, T_, S_, (long)C_ * S_, (long)T_ * S_, (long)C_ * T_,
      nullptr, nullptr, nullptr, nullptr, ctx);

  (void)in_sizes; (void)n_in; (void)out_size; (void)ws_size;
}

// Round 7
// 298.916 us; speedup vs baseline: 1.0951x; 1.0951x over previous
//
#include <hip/hip_runtime.h>

typedef unsigned short u16;
typedef __attribute__((ext_vector_type(4))) float f4;
typedef __attribute__((ext_vector_type(8))) short bf8;
typedef __attribute__((ext_vector_type(4))) unsigned short u16x4;

#define B_ 8
#define C_ 512
#define T_ 2048
#define S_ 2048
#define SCALE_W 0.70710678118654752440f

__device__ __forceinline__ u16 f2bf(float f) {
  unsigned u = __builtin_bit_cast(unsigned, f);
  unsigned r = 0x7FFFu + ((u >> 16) & 1u);
  return (u16)((u + r) >> 16);
}
__device__ __forceinline__ float bf2f(u16 h) {
  unsigned u = ((unsigned)h) << 16;
  return __builtin_bit_cast(float, u);
}

__device__ __forceinline__ void gload16(const u16* g, u16* l) {
  __builtin_amdgcn_global_load_lds((__attribute__((address_space(1))) const void*)g,
                                   (__attribute__((address_space(3))) void*)l, 16, 0, 0);
}

#define MEMF() asm volatile("" ::: "memory")
#define BAR()  do { MEMF(); __builtin_amdgcn_s_barrier(); MEMF(); } while (0)
#define LGKM0() do { asm volatile("s_waitcnt lgkmcnt(0)" ::: "memory"); \
                     __builtin_amdgcn_sched_barrier(0); } while (0)

// ---------- prep: transpose [B,C,X] -> [B,X,C], split to bf16 hi/lo
__global__ __launch_bounds__(256) void transpose_kernel(
    const float* __restrict__ in, u16* __restrict__ oh, u16* __restrict__ ol, int X)
{
  __shared__ float t[32][33];
  const int tx = threadIdx.x, ty = threadIdx.y;
  const long cbase = (long)blockIdx.z * C_ + blockIdx.y * 32;
  const long xbase = (long)blockIdx.x * 32;
  const float* ip = in + cbase * X + xbase;
#pragma unroll
  for (int i = 0; i < 4; ++i)
    t[ty + i * 8][tx] = ip[(long)(ty + i * 8) * X + tx];
  __syncthreads();
  const long obase = ((long)blockIdx.z * X + xbase) * C_ + blockIdx.y * 32;
#pragma unroll
  for (int i = 0; i < 4; ++i) {
    float v = t[tx][ty + i * 8];
    long idx = obase + (long)(ty + i * 8) * C_ + tx;
    u16 h = f2bf(v);
    oh[idx] = h;
    ol[idx] = f2bf(v - bf2f(h));
  }
}

// ---------- prep: elementwise split f32 -> bf16 hi (and optional lo)
__global__ __launch_bounds__(256) void split_kernel(
    const float* __restrict__ in, u16* __restrict__ oh, u16* __restrict__ ol, long n4)
{
  long i = (long)blockIdx.x * 256 + threadIdx.x;
  const long stride = (long)gridDim.x * 256;
  for (; i < n4; i += stride) {
    f4 v = ((const f4*)in)[i];
    u16x4 hv, lv;
#pragma unroll
    for (int j = 0; j < 4; ++j) {
      u16 h = f2bf(v[j]);
      hv[j] = h;
      lv[j] = f2bf(v[j] - bf2f(h));
    }
    ((u16x4*)oh)[i] = hv;
    if (ol) ((u16x4*)ol)[i] = lv;
  }
}

// ---------- old-structure GEMM (128x128, BK=32): out[M][N] = A[M][K] * B[N][K]^T
// NPASS=3: hi/lo 3-pass. EPI=1: +base(original [B,C,T] layout)+bias, *SCALE, hi/lo store.
template<int NPASS, int EPI>
__global__ __launch_bounds__(256, 2) void gemm_kernel(
    const u16* __restrict__ Ah, const u16* __restrict__ Al,
    const u16* __restrict__ Bh, const u16* __restrict__ Bl,
    int M, int N, int K,
    long sA, long sB, long sO,
    const float* __restrict__ baseO, const float* __restrict__ bias,
    u16* __restrict__ outH, u16* __restrict__ outL,
    float* __restrict__ outF)
{
  constexpr int BM = 128, BK = 32;
  constexpr int TILE = BM * BK;
  __shared__ u16 lA[(NPASS == 3 ? 2 : 1) * TILE];
  __shared__ u16 lB[(NPASS == 3 ? 2 : 1) * TILE];
  u16* lAh = lA; u16* lAl = (NPASS == 3) ? (lA + TILE) : lA;
  u16* lBh = lB; u16* lBl = (NPASS == 3) ? (lB + TILE) : lB;

  const int tid = threadIdx.x;
  const int wid = tid >> 6;
  const int lane = tid & 63;
  const int wr = wid >> 1, wc = wid & 1;
  const int bz = blockIdx.z;
  const int m0 = blockIdx.y * BM;
  const int n0 = blockIdx.x * BM;

  const u16* gAh = Ah + (long)bz * sA + (long)m0 * K;
  const u16* gAl = (NPASS == 3) ? (Al + (long)bz * sA + (long)m0 * K) : nullptr;
  const u16* gBh = Bh + (long)bz * sB + (long)n0 * K;
  const u16* gBl = (NPASS == 3) ? (Bl + (long)bz * sB + (long)n0 * K) : nullptr;

  const int srow = tid >> 2;
  const int skoff = (tid & 3) * 8;
  const int ldsOff = wid * 512;

  f4 acc[4][4] = {};

  for (int k0 = 0; k0 < K; k0 += BK) {
    __syncthreads();
#pragma unroll
    for (int c = 0; c < 2; ++c) {
      const long go = (long)(c * 64 + srow) * K + k0 + skoff;
      const int lo = c * 2048 + ldsOff;
      gload16(gAh + go, lAh + lo);
      if (NPASS == 3) gload16(gAl + go, lAl + lo);
      gload16(gBh + go, lBh + lo);
      if (NPASS == 3) gload16(gBl + go, lBl + lo);
    }
    asm volatile("s_waitcnt vmcnt(0)" ::: "memory");
    __syncthreads();

    bf8 a_h[4], b_h[4], a_l[4], b_l[4];
    const int fr = lane & 15;
    const int fk = (lane >> 4) * 8;
#pragma unroll
    for (int i = 0; i < 4; ++i) {
      a_h[i] = *(const bf8*)&lAh[(wr * 64 + i * 16 + fr) * BK + fk];
      b_h[i] = *(const bf8*)&lBh[(wc * 64 + i * 16 + fr) * BK + fk];
      if (NPASS == 3) {
        a_l[i] = *(const bf8*)&lAl[(wr * 64 + i * 16 + fr) * BK + fk];
        b_l[i] = *(const bf8*)&lBl[(wc * 64 + i * 16 + fr) * BK + fk];
      }
    }
#pragma unroll
    for (int mi = 0; mi < 4; ++mi)
#pragma unroll
      for (int ni = 0; ni < 4; ++ni) {
        acc[mi][ni] = __builtin_amdgcn_mfma_f32_16x16x32_bf16(a_h[mi], b_h[ni], acc[mi][ni], 0, 0, 0);
        if (NPASS == 3) {
          acc[mi][ni] = __builtin_amdgcn_mfma_f32_16x16x32_bf16(a_h[mi], b_l[ni], acc[mi][ni], 0, 0, 0);
          acc[mi][ni] = __builtin_amdgcn_mfma_f32_16x16x32_bf16(a_l[mi], b_h[ni], acc[mi][ni], 0, 0, 0);
        }
      }
  }

  const int fr = lane & 15;
  const int r4 = (lane >> 4) * 4;
#pragma unroll
  for (int mi = 0; mi < 4; ++mi) {
#pragma unroll
    for (int ni = 0; ni < 4; ++ni) {
      const int gn = n0 + wc * 64 + ni * 16 + fr;
      const long gmb = m0 + wr * 64 + mi * 16 + r4;
      if (EPI == 1) {
        // base in original [B][C][T] layout: channel gn, t = gmb..gmb+3 (f4 aligned)
        f4 bv = *(const f4*)(baseO + ((long)bz * C_ + gn) * T_ + gmb);
        const float bs = bias[gn];
#pragma unroll
        for (int r = 0; r < 4; ++r) {
          float val = (acc[mi][ni][r] + bv[r] + bs) * SCALE_W;
          const long idx = (long)bz * sO + (gmb + r) * (long)N + gn;
          u16 h = f2bf(val);
          outH[idx] = h;
          outL[idx] = f2bf(val - bf2f(h));
        }
      } else {
#pragma unroll
        for (int r = 0; r < 4; ++r)
          outF[(long)bz * sO + (gmb + r) * (long)N + gn] = acc[mi][ni][r];
      }
    }
  }
}

// ---------- 256x256 / BK=64 / 8-wave phase-pipelined GEMM (counted vmcnt)
// LDS slot swizzle: a row is 8 slots of 16B; store LDS[R][slot ^ (R&7)].
// Any 8 consecutive lanes of a ds_read_b128 then cover all 8 slots = all 32
// banks exactly once (fr&7 = 0..7 within each octet) -> conflict-free floor.
// Computes pre_a[t][s] = Ah.Bh + Ah.Bl + Al.Bh over K=512 via 24 k-tiles of 64:
// tiles 0-7: Ah x Bh; 8-15: Ah x Bl; 16-23: Al x Bh. All operands K-contiguous, stride C_.
__device__ __forceinline__ void stage2(const u16* g, u16* l) {
  gload16(g, l);
  gload16(g + 64 * C_, l + 4096);   // +64 rows: (row+64)&7 unchanged -> same swizzle
}
template<int NF>
__device__ __forceinline__ void rd_frags(bf8 (&d)[NF][2], const u16* p, int k0o, int k1o) {
#pragma unroll
  for (int i = 0; i < NF; ++i) {
    d[i][0] = *(const bf8*)&p[i * 1024 + k0o];
    d[i][1] = *(const bf8*)&p[i * 1024 + k1o];
  }
}
template<int MH, int NH>
__device__ __forceinline__ void mmq(f4 (&acc)[8][4], const bf8 (&a)[4][2], const bf8 (&b)[2][2]) {
  __builtin_amdgcn_s_setprio(1);
#pragma unroll
  for (int mi = 0; mi < 4; ++mi)
#pragma unroll
    for (int ni = 0; ni < 2; ++ni)
#pragma unroll
      for (int ks = 0; ks < 2; ++ks)
        acc[MH * 4 + mi][NH * 2 + ni] = __builtin_amdgcn_mfma_f32_16x16x32_bf16(
            a[mi][ks], b[ni][ks], acc[MH * 4 + mi][NH * 2 + ni], 0, 0, 0);
  __builtin_amdgcn_s_setprio(0);
}

__global__ __launch_bounds__(512, 2) void gemm8p_kernel(
    const u16* __restrict__ Ah, const u16* __restrict__ Al,
    const u16* __restrict__ Bh, const u16* __restrict__ Bl,
    float* __restrict__ outF)
{
  __shared__ u16 lds[65536];  // A: [2buf][256r][64c] @0 ; B: same @32768 (u16 units)
  const int tid = threadIdx.x;
  const int wid = tid >> 6, lane = tid & 63;
  const int wr = wid >> 2, wc = wid & 3;

  // bijective XCD swizzle (nwg = 512, divisible by 8)
  const int gx = gridDim.x, gy = gridDim.y;
  int lin = blockIdx.x + gx * (blockIdx.y + gy * blockIdx.z);
  const int nwg = gx * gy * (int)gridDim.z;
  lin = (lin & 7) * (nwg >> 3) + (lin >> 3);
  const int bx = lin % gx;
  const int tmp = lin / gx;
  const int by = tmp % gy, bz = tmp / gy;

  const int m0 = by * 256, n0 = bx * 256;
  const u16* gAh = Ah + ((long)bz * T_ + m0) * C_;
  const u16* gAl = Al + ((long)bz * T_ + m0) * C_;
  const u16* gBh = Bh + ((long)bz * S_ + n0) * C_;
  const u16* gBl = Bl + ((long)bz * S_ + n0) * C_;

  // staging geometry: per half-tile (128 rows x 64 u16 cols), 2 gloads/thread.
  // LDS dest linear (slot = tid&7); source slot = (tid&7) ^ (srow&7).
  const int srow = tid >> 3;                                   // 0..63
  const int scol = (((tid & 7) ^ (srow & 7)) * 8);             // u16
  const int dstA = tid * 8;                                    // u16

  // fragment-read geometry: nominal slot = ks*4 + g (g = lane>>4);
  // swizzled u16 col = ((ks*4 + g) ^ (fr&7)) * 8; fr&7 == lane&7.
  const int fr = lane & 15;
  const int k0o = (((lane >> 4) ^ (lane & 7)) * 8);            // ks=0
  const int k1o = k0o ^ 32;                                    // ks=1 (slot bit 2)
  const int abase = (wr * 128 + fr) * 64;
  const int bbase = 32768 + (wc * 64 + fr) * 64;

  f4 acc[8][4] = {};
  constexpr int NT = 24;

#define SRC_A(tt) ((((tt) >> 3) == 2 ? gAl : gAh) + ((tt) & 7) * 64)
#define SRC_B(tt) ((((tt) >> 3) == 1 ? gBl : gBh) + ((tt) & 7) * 64)
#define STAGE_A(tt, h) stage2(SRC_A(tt) + (long)((h) * 128 + srow) * C_ + scol, \
                              lds + (((tt) & 1) * 16384 + (h) * 8192 + dstA))
#define STAGE_B(tt, h) stage2(SRC_B(tt) + (long)((h) * 128 + srow) * C_ + scol, \
                              lds + (32768 + ((tt) & 1) * 16384 + (h) * 8192 + dstA))

  // prologue: tile0 fully + B(1,0) (10 loads in flight)
  STAGE_B(0, 0); STAGE_B(0, 1); STAGE_A(0, 0); STAGE_A(0, 1); STAGE_B(1, 0);
  asm volatile("s_waitcnt vmcnt(2)" ::: "memory");  // tile0 landed; B(1)h0 may fly
  BAR();

  bf8 af[4][2], b0[2][2], b1[2][2];
  for (int kt = 0; kt < NT - 1; ++kt) {
    const int cur = kt & 1;
    const u16* la = lds + cur * 16384 + abase;
    const u16* lb = lds + cur * 16384 + bbase;
    // ---- ph1: Q(0,0)
    rd_frags(af, la, k0o, k1o);
    rd_frags(b0, lb, k0o, k1o);
    STAGE_B(kt + 1, 1);
    BAR(); LGKM0();
    mmq<0, 0>(acc, af, b0);
    BAR();
    // ---- ph2: Q(0,1)
    rd_frags(b1, lb + 2048, k0o, k1o);
    STAGE_A(kt + 1, 0);
    BAR(); LGKM0();
    mmq<0, 1>(acc, af, b1);
    BAR();
    // ---- ph3: Q(1,0)
    rd_frags(af, la + 4096, k0o, k1o);
    STAGE_A(kt + 1, 1);
    BAR(); LGKM0();
    mmq<1, 0>(acc, af, b0);
    BAR();
    // ---- ph4: Q(1,1)
    {
      int t2 = kt + 2; if (t2 > NT - 1) t2 = NT - 1;  // harmless duplicate re-stage at tail
      STAGE_B(t2, 0);
    }
    BAR();
    mmq<1, 1>(acc, af, b1);
    if (kt == NT - 2) { asm volatile("s_waitcnt vmcnt(0)" ::: "memory"); }
    else             { asm volatile("s_waitcnt vmcnt(2)" ::: "memory"); }
    BAR();
  }
  // peeled final tile (no staging)
  {
    const int cur = (NT - 1) & 1;
    const u16* la = lds + cur * 16384 + abase;
    const u16* lb = lds + cur * 16384 + bbase;
    rd_frags(af, la, k0o, k1o);
    rd_frags(b0, lb, k0o, k1o);
    BAR(); LGKM0();
    mmq<0, 0>(acc, af, b0);
    BAR();
    rd_frags(b1, lb + 2048, k0o, k1o);
    BAR(); LGKM0();
    mmq<0, 1>(acc, af, b1);
    BAR();
    rd_frags(af, la + 4096, k0o, k1o);
    BAR(); LGKM0();
    mmq<1, 0>(acc, af, b0);
    BAR();
    mmq<1, 1>(acc, af, b1);
  }
#undef SRC_A
#undef SRC_B
#undef STAGE_A
#undef STAGE_B

  // epilogue: f32 C-write to attn [T][S]
  const int r4 = (lane >> 4) * 4;
#pragma unroll
  for (int am = 0; am < 8; ++am) {
#pragma unroll
    for (int an = 0; an < 4; ++an) {
      const long gm = m0 + wr * 128 + am * 16 + r4;
      const int gn = n0 + wc * 64 + an * 16 + fr;
      float* po = outF + (long)bz * T_ * S_ + gm * (long)S_ + gn;
#pragma unroll
      for (int r = 0; r < 4; ++r) po[(long)r * S_] = acc[am][an][r];
    }
  }
}

// ---------- softmax over last dim (rows of 2048 f32), in place + bf16 copy out
__global__ __launch_bounds__(256) void softmax_kernel(float* __restrict__ a,
                                                      u16* __restrict__ ab) {
  const int tid = threadIdx.x;
  float* p = a + (long)blockIdx.x * 2048;
  u16* pb = ab + (long)blockIdx.x * 2048;
  f4 v0 = ((const f4*)p)[tid];
  f4 v1 = ((const f4*)p)[tid + 256];
  float m = fmaxf(fmaxf(fmaxf(v0[0], v0[1]), fmaxf(v0[2], v0[3])),
                  fmaxf(fmaxf(v1[0], v1[1]), fmaxf(v1[2], v1[3])));
#pragma unroll
  for (int o = 32; o >= 1; o >>= 1) m = fmaxf(m, __shfl_xor(m, o));
  __shared__ float redm[4], reds[4];
  if ((tid & 63) == 0) redm[tid >> 6] = m;
  __syncthreads();
  m = fmaxf(fmaxf(redm[0], redm[1]), fmaxf(redm[2], redm[3]));
  float s = 0.f;
#pragma unroll
  for (int j = 0; j < 4; ++j) { v0[j] = __expf(v0[j] - m); s += v0[j]; }
#pragma unroll
  for (int j = 0; j < 4; ++j) { v1[j] = __expf(v1[j] - m); s += v1[j]; }
#pragma unroll
  for (int o = 32; o >= 1; o >>= 1) s += __shfl_xor(s, o);
  if ((tid & 63) == 0) reds[tid >> 6] = s;
  __syncthreads();
  const float inv = 1.0f / (reds[0] + reds[1] + reds[2] + reds[3]);
  v0 *= inv; v1 *= inv;
  ((f4*)p)[tid] = v0;
  ((f4*)p)[tid + 256] = v1;
  u16x4 c0, c1;
#pragma unroll
  for (int j = 0; j < 4; ++j) { c0[j] = f2bf(v0[j]); c1[j] = f2bf(v1[j]); }
  ((u16x4*)pb)[tid] = c0;
  ((u16x4*)pb)[tid + 256] = c1;
}

extern "C" void kernel_launch(void* const* d_in, const int* in_sizes, int n_in,
                              void* d_out, int out_size, void* d_ws, size_t ws_size,
                              hipStream_t stream) {
  const float* base  = (const float*)d_in[0];
  const float* x     = (const float*)d_in[1];
  const float* enc_t = (const float*)d_in[2];
  const float* enc_c = (const float*)d_in[3];
  const float* W     = (const float*)d_in[4];
  const float* bias  = (const float*)d_in[5];

  float* ctx  = (float*)d_out;                       // [B,C,T]
  float* attn = ctx + (long)B_ * C_ * T_;            // [B,T,S]

  const long NBTC = (long)B_ * T_ * C_;              // 8388608
  u16* x_hi  = (u16*)d_ws;
  u16* x_lo  = x_hi + NBTC;
  u16* et_hi = x_lo + NBTC;
  u16* et_lo = et_hi + NBTC;
  u16* ec_hi = et_lo + NBTC;
  u16* w_hi  = ec_hi + NBTC;
  u16* w_lo  = w_hi + (long)C_ * C_;

  // target hi/lo splits in d_out ctx region (2*NBTC u16 = exactly 32 MB, dead until GEMM3)
  u16* t_hi = (u16*)d_out;
  u16* t_lo = t_hi + NBTC;
  // attn bf16 copy aliases x_hi..et_lo (exactly 4*NBTC u16 = B*T*S), all dead after GEMM2
  u16* attn_bf = x_hi;

  dim3 tb(32, 8);
  // x [B,C,T] -> x_hi/x_lo [B,T,C]
  transpose_kernel<<<dim3(T_ / 32, C_ / 32, B_), tb, 0, stream>>>(x, x_hi, x_lo, T_);
  // enc_t [B,C,S] -> et_hi/et_lo [B,S,C]
  transpose_kernel<<<dim3(S_ / 32, C_ / 32, B_), tb, 0, stream>>>(enc_t, et_hi, et_lo, S_);
  // enc_c -> ec_hi bf16 (no transpose, hi only)
  split_kernel<<<2048, 256, 0, stream>>>(enc_c, ec_hi, nullptr, (long)B_ * C_ * S_ / 4);
  // W -> w_hi/w_lo
  split_kernel<<<256, 256, 0, stream>>>(W, w_hi, w_lo, (long)C_ * C_ / 4);

  // GEMM1 (old structure, 3-pass): target^T[t][o] = sum_c x^T[t][c]*W[o][c];
  // epilogue +base(original layout)+bias, *scale, hi/lo store
  gemm_kernel<3, 1><<<dim3(C_ / 128, T_ / 128, B_), 256, 0, stream>>>(
      x_hi, x_lo, w_hi, w_lo,
      T_, C_, C_, (long)T_ * C_, 0L, (long)T_ * C_,
      base, bias, t_hi, t_lo, nullptr);

  // GEMM2 (256x256 8-phase, 24 k-tiles with hi/lo pointer switching) -> attn f32
  gemm8p_kernel<<<dim3(S_ / 256, T_ / 256, B_), 512, 0, stream>>>(
      t_hi, t_lo, et_hi, et_lo, attn);

  // softmax rows in place + bf16 copy
  softmax_kernel<<<B_ * T_, 256, 0, stream>>>(attn, attn_bf);

  // GEMM3 (old structure, 1-pass): ctx[c][t] = sum_s ec[c][s] * attn_bf[t][s]
  gemm_kernel<1, 0><<<dim3(T_ / 128, C_ / 128, B_), 256, 0, stream>>>(
      ec_hi, nullptr, attn_bf, nullptr,
      C_, T_, S_, (long)C_ * S_, (long)T_ * S_, (long)C_ * T_,
      nullptr, nullptr, nullptr, nullptr, ctx);

  (void)in_sizes; (void)n_in; (void)out_size; (void)ws_size;
}

// Round 8
// 270.428 us; speedup vs baseline: 1.2104x; 1.1053x over previous
//
#include <hip/hip_runtime.h>

typedef unsigned short u16;
typedef __attribute__((ext_vector_type(4))) float f4;
typedef __attribute__((ext_vector_type(8))) short bf8;
typedef __attribute__((ext_vector_type(8))) _Float16 h8;
typedef __attribute__((ext_vector_type(4))) unsigned short u16x4;

#define B_ 8
#define C_ 512
#define T_ 2048
#define S_ 2048
#define SCALE_W 0.70710678118654752440f

__device__ __forceinline__ u16 f2bf(float f) {
  unsigned u = __builtin_bit_cast(unsigned, f);
  unsigned r = 0x7FFFu + ((u >> 16) & 1u);
  return (u16)((u + r) >> 16);
}
__device__ __forceinline__ float bf2f(u16 h) {
  unsigned u = ((unsigned)h) << 16;
  return __builtin_bit_cast(float, u);
}
__device__ __forceinline__ u16 f2h(float f) {
  return __builtin_bit_cast(u16, (_Float16)f);
}
__device__ __forceinline__ float h2f(u16 h) {
  return (float)__builtin_bit_cast(_Float16, h);
}

__device__ __forceinline__ void gload16(const u16* g, u16* l) {
  __builtin_amdgcn_global_load_lds((__attribute__((address_space(1))) const void*)g,
                                   (__attribute__((address_space(3))) void*)l, 16, 0, 0);
}

#define MEMF() asm volatile("" ::: "memory")
#define BAR()  do { MEMF(); __builtin_amdgcn_s_barrier(); MEMF(); } while (0)
#define LGKM0() do { asm volatile("s_waitcnt lgkmcnt(0)" ::: "memory"); \
                     __builtin_amdgcn_sched_barrier(0); } while (0)

// ---------- prep: transpose [B,C,X] -> [B,X,C].
// MODE 0: split to bf16 hi/lo. MODE 1: single fp16.
template<int MODE>
__global__ __launch_bounds__(256) void transpose_kernel(
    const float* __restrict__ in, u16* __restrict__ oh, u16* __restrict__ ol, int X)
{
  __shared__ float t[32][33];
  const int tx = threadIdx.x, ty = threadIdx.y;
  const long cbase = (long)blockIdx.z * C_ + blockIdx.y * 32;
  const long xbase = (long)blockIdx.x * 32;
  const float* ip = in + cbase * X + xbase;
#pragma unroll
  for (int i = 0; i < 4; ++i)
    t[ty + i * 8][tx] = ip[(long)(ty + i * 8) * X + tx];
  __syncthreads();
  const long obase = ((long)blockIdx.z * X + xbase) * C_ + blockIdx.y * 32;
#pragma unroll
  for (int i = 0; i < 4; ++i) {
    float v = t[tx][ty + i * 8];
    long idx = obase + (long)(ty + i * 8) * C_ + tx;
    if (MODE == 0) {
      u16 h = f2bf(v);
      oh[idx] = h;
      ol[idx] = f2bf(v - bf2f(h));
    } else {
      oh[idx] = f2h(v);
    }
  }
}

// ---------- prep: elementwise convert. FP16=0: bf16 hi/lo; FP16=1: fp16 single.
template<int FP16>
__global__ __launch_bounds__(256) void split_kernel(
    const float* __restrict__ in, u16* __restrict__ oh, u16* __restrict__ ol, long n4)
{
  long i = (long)blockIdx.x * 256 + threadIdx.x;
  const long stride = (long)gridDim.x * 256;
  for (; i < n4; i += stride) {
    f4 v = ((const f4*)in)[i];
    u16x4 hv, lv;
#pragma unroll
    for (int j = 0; j < 4; ++j) {
      if (FP16) {
        hv[j] = f2h(v[j]);
      } else {
        u16 h = f2bf(v[j]);
        hv[j] = h;
        lv[j] = f2bf(v[j] - bf2f(h));
      }
    }
    ((u16x4*)oh)[i] = hv;
    if (!FP16) ((u16x4*)ol)[i] = lv;
  }
}

// ---------- old-structure GEMM (128x128, BK=32): out[M][N] = A[M][K] * B[N][K]^T
// NPASS=3: hi/lo 3-pass. F16: mfma dtype. EPI=1: +base+bias, *SCALE, fp16 hi/lo store.
template<int NPASS, int EPI, int F16>
__global__ __launch_bounds__(256, 2) void gemm_kernel(
    const u16* __restrict__ Ah, const u16* __restrict__ Al,
    const u16* __restrict__ Bh, const u16* __restrict__ Bl,
    int M, int N, int K,
    long sA, long sB, long sO,
    const float* __restrict__ baseO, const float* __restrict__ bias,
    u16* __restrict__ outH, u16* __restrict__ outL,
    float* __restrict__ outF)
{
  constexpr int BM = 128, BK = 32;
  constexpr int TILE = BM * BK;
  __shared__ u16 lA[(NPASS == 3 ? 2 : 1) * TILE];
  __shared__ u16 lB[(NPASS == 3 ? 2 : 1) * TILE];
  u16* lAh = lA; u16* lAl = (NPASS == 3) ? (lA + TILE) : lA;
  u16* lBh = lB; u16* lBl = (NPASS == 3) ? (lB + TILE) : lB;

  const int tid = threadIdx.x;
  const int wid = tid >> 6;
  const int lane = tid & 63;
  const int wr = wid >> 1, wc = wid & 1;
  const int bz = blockIdx.z;
  const int m0 = blockIdx.y * BM;
  const int n0 = blockIdx.x * BM;

  const u16* gAh = Ah + (long)bz * sA + (long)m0 * K;
  const u16* gAl = (NPASS == 3) ? (Al + (long)bz * sA + (long)m0 * K) : nullptr;
  const u16* gBh = Bh + (long)bz * sB + (long)n0 * K;
  const u16* gBl = (NPASS == 3) ? (Bl + (long)bz * sB + (long)n0 * K) : nullptr;

  const int srow = tid >> 2;
  const int skoff = (tid & 3) * 8;
  const int ldsOff = wid * 512;

  f4 acc[4][4] = {};

#define MM(a, b, c) (F16 ? __builtin_amdgcn_mfma_f32_16x16x32_f16( \
                       __builtin_bit_cast(h8, a), __builtin_bit_cast(h8, b), c, 0, 0, 0) \
                         : __builtin_amdgcn_mfma_f32_16x16x32_bf16(a, b, c, 0, 0, 0))

  for (int k0 = 0; k0 < K; k0 += BK) {
    __syncthreads();
#pragma unroll
    for (int c = 0; c < 2; ++c) {
      const long go = (long)(c * 64 + srow) * K + k0 + skoff;
      const int lo = c * 2048 + ldsOff;
      gload16(gAh + go, lAh + lo);
      if (NPASS == 3) gload16(gAl + go, lAl + lo);
      gload16(gBh + go, lBh + lo);
      if (NPASS == 3) gload16(gBl + go, lBl + lo);
    }
    asm volatile("s_waitcnt vmcnt(0)" ::: "memory");
    __syncthreads();

    bf8 a_h[4], b_h[4], a_l[4], b_l[4];
    const int fr = lane & 15;
    const int fk = (lane >> 4) * 8;
#pragma unroll
    for (int i = 0; i < 4; ++i) {
      a_h[i] = *(const bf8*)&lAh[(wr * 64 + i * 16 + fr) * BK + fk];
      b_h[i] = *(const bf8*)&lBh[(wc * 64 + i * 16 + fr) * BK + fk];
      if (NPASS == 3) {
        a_l[i] = *(const bf8*)&lAl[(wr * 64 + i * 16 + fr) * BK + fk];
        b_l[i] = *(const bf8*)&lBl[(wc * 64 + i * 16 + fr) * BK + fk];
      }
    }
#pragma unroll
    for (int mi = 0; mi < 4; ++mi)
#pragma unroll
      for (int ni = 0; ni < 4; ++ni) {
        acc[mi][ni] = MM(a_h[mi], b_h[ni], acc[mi][ni]);
        if (NPASS == 3) {
          acc[mi][ni] = MM(a_h[mi], b_l[ni], acc[mi][ni]);
          acc[mi][ni] = MM(a_l[mi], b_h[ni], acc[mi][ni]);
        }
      }
  }
#undef MM

  const int fr = lane & 15;
  const int r4 = (lane >> 4) * 4;
#pragma unroll
  for (int mi = 0; mi < 4; ++mi) {
#pragma unroll
    for (int ni = 0; ni < 4; ++ni) {
      const int gn = n0 + wc * 64 + ni * 16 + fr;
      const long gmb = m0 + wr * 64 + mi * 16 + r4;
      if (EPI == 1) {
        // base in original [B][C][T] layout: channel gn, t = gmb..gmb+3 (f4 aligned)
        f4 bv = *(const f4*)(baseO + ((long)bz * C_ + gn) * T_ + gmb);
        const float bs = bias[gn];
#pragma unroll
        for (int r = 0; r < 4; ++r) {
          float val = (acc[mi][ni][r] + bv[r] + bs) * SCALE_W;
          const long idx = (long)bz * sO + (gmb + r) * (long)N + gn;
          u16 h = f2h(val);
          outH[idx] = h;
          outL[idx] = f2h(val - h2f(h));
        }
      } else {
#pragma unroll
        for (int r = 0; r < 4; ++r)
          outF[(long)bz * sO + (gmb + r) * (long)N + gn] = acc[mi][ni][r];
      }
    }
  }
}

// ---------- 256x256 / BK=64 / 8-wave phase-pipelined fp16 GEMM (counted vmcnt)
// LDS slot swizzle (round-7, proven conflict-free): store LDS[R][slot ^ (R&7)].
// Computes pre_a[t][s] = Th.E + Tl.E over K=512 via 16 k-tiles of 64:
// tiles 0-7: Th x E; 8-15: Tl x E. T split is exact in fp16, E single fp16.
__device__ __forceinline__ void stage2(const u16* g, u16* l) {
  gload16(g, l);
  gload16(g + 64 * C_, l + 4096);   // +64 rows: (row+64)&7 unchanged -> same swizzle
}
template<int NF>
__device__ __forceinline__ void rd_frags(bf8 (&d)[NF][2], const u16* p, int k0o, int k1o) {
#pragma unroll
  for (int i = 0; i < NF; ++i) {
    d[i][0] = *(const bf8*)&p[i * 1024 + k0o];
    d[i][1] = *(const bf8*)&p[i * 1024 + k1o];
  }
}
template<int MH, int NH>
__device__ __forceinline__ void mmq(f4 (&acc)[8][4], const bf8 (&a)[4][2], const bf8 (&b)[2][2]) {
  __builtin_amdgcn_s_setprio(1);
#pragma unroll
  for (int mi = 0; mi < 4; ++mi)
#pragma unroll
    for (int ni = 0; ni < 2; ++ni)
#pragma unroll
      for (int ks = 0; ks < 2; ++ks)
        acc[MH * 4 + mi][NH * 2 + ni] = __builtin_amdgcn_mfma_f32_16x16x32_f16(
            __builtin_bit_cast(h8, a[mi][ks]), __builtin_bit_cast(h8, b[ni][ks]),
            acc[MH * 4 + mi][NH * 2 + ni], 0, 0, 0);
  __builtin_amdgcn_s_setprio(0);
}

__global__ __launch_bounds__(512, 2) void gemm8p_kernel(
    const u16* __restrict__ Ah, const u16* __restrict__ Al,
    const u16* __restrict__ Bm,
    float* __restrict__ outF)
{
  __shared__ u16 lds[65536];  // A: [2buf][256r][64c] @0 ; B: same @32768 (u16 units)
  const int tid = threadIdx.x;
  const int wid = tid >> 6, lane = tid & 63;
  const int wr = wid >> 2, wc = wid & 3;

  // bijective XCD swizzle (nwg = 512, divisible by 8)
  const int gx = gridDim.x, gy = gridDim.y;
  int lin = blockIdx.x + gx * (blockIdx.y + gy * blockIdx.z);
  const int nwg = gx * gy * (int)gridDim.z;
  lin = (lin & 7) * (nwg >> 3) + (lin >> 3);
  const int bx = lin % gx;
  const int tmp = lin / gx;
  const int by = tmp % gy, bz = tmp / gy;

  const int m0 = by * 256, n0 = bx * 256;
  const u16* gAh = Ah + ((long)bz * T_ + m0) * C_;
  const u16* gAl = Al + ((long)bz * T_ + m0) * C_;
  const u16* gB  = Bm + ((long)bz * S_ + n0) * C_;

  // staging geometry: per half-tile (128 rows x 64 u16 cols), 2 gloads/thread.
  // LDS dest linear (slot = tid&7); source slot = (tid&7) ^ (srow&7).
  const int srow = tid >> 3;                                   // 0..63
  const int scol = (((tid & 7) ^ (srow & 7)) * 8);             // u16
  const int dstA = tid * 8;                                    // u16

  // fragment-read: nominal slot = ks*4 + g; swizzled col = ((ks*4+g) ^ (lane&7))*8
  const int fr = lane & 15;
  const int k0o = (((lane >> 4) ^ (lane & 7)) * 8);            // ks=0
  const int k1o = k0o ^ 32;                                    // ks=1 (slot bit 2)
  const int abase = (wr * 128 + fr) * 64;
  const int bbase = 32768 + (wc * 64 + fr) * 64;

  f4 acc[8][4] = {};
  constexpr int NT = 16;

#define SRC_A(tt) ((((tt) >> 3) ? gAl : gAh) + ((tt) & 7) * 64)
#define SRC_B(tt) (gB + ((tt) & 7) * 64)
#define STAGE_A(tt, h) stage2(SRC_A(tt) + (long)((h) * 128 + srow) * C_ + scol, \
                              lds + (((tt) & 1) * 16384 + (h) * 8192 + dstA))
#define STAGE_B(tt, h) stage2(SRC_B(tt) + (long)((h) * 128 + srow) * C_ + scol, \
                              lds + (32768 + ((tt) & 1) * 16384 + (h) * 8192 + dstA))

  // prologue: tile0 fully + B(1,0) (10 loads in flight)
  STAGE_B(0, 0); STAGE_B(0, 1); STAGE_A(0, 0); STAGE_A(0, 1); STAGE_B(1, 0);
  asm volatile("s_waitcnt vmcnt(2)" ::: "memory");  // tile0 landed; B(1)h0 may fly
  BAR();

  bf8 af[4][2], b0[2][2], b1[2][2];
  for (int kt = 0; kt < NT - 1; ++kt) {
    const int cur = kt & 1;
    const u16* la = lds + cur * 16384 + abase;
    const u16* lb = lds + cur * 16384 + bbase;
    // ---- ph1: Q(0,0)
    rd_frags(af, la, k0o, k1o);
    rd_frags(b0, lb, k0o, k1o);
    STAGE_B(kt + 1, 1);
    BAR(); LGKM0();
    mmq<0, 0>(acc, af, b0);
    BAR();
    // ---- ph2: Q(0,1)
    rd_frags(b1, lb + 2048, k0o, k1o);
    STAGE_A(kt + 1, 0);
    BAR(); LGKM0();
    mmq<0, 1>(acc, af, b1);
    BAR();
    // ---- ph3: Q(1,0)
    rd_frags(af, la + 4096, k0o, k1o);
    STAGE_A(kt + 1, 1);
    BAR(); LGKM0();
    mmq<1, 0>(acc, af, b0);
    BAR();
    // ---- ph4: Q(1,1)
    {
      int t2 = kt + 2; if (t2 > NT - 1) t2 = NT - 1;  // harmless duplicate re-stage at tail
      STAGE_B(t2, 0);
    }
    BAR();
    mmq<1, 1>(acc, af, b1);
    if (kt == NT - 2) { asm volatile("s_waitcnt vmcnt(0)" ::: "memory"); }
    else             { asm volatile("s_waitcnt vmcnt(2)" ::: "memory"); }
    BAR();
  }
  // peeled final tile (no staging)
  {
    const int cur = (NT - 1) & 1;
    const u16* la = lds + cur * 16384 + abase;
    const u16* lb = lds + cur * 16384 + bbase;
    rd_frags(af, la, k0o, k1o);
    rd_frags(b0, lb, k0o, k1o);
    BAR(); LGKM0();
    mmq<0, 0>(acc, af, b0);
    BAR();
    rd_frags(b1, lb + 2048, k0o, k1o);
    BAR(); LGKM0();
    mmq<0, 1>(acc, af, b1);
    BAR();
    rd_frags(af, la + 4096, k0o, k1o);
    BAR(); LGKM0();
    mmq<1, 0>(acc, af, b0);
    BAR();
    mmq<1, 1>(acc, af, b1);
  }
#undef SRC_A
#undef SRC_B
#undef STAGE_A
#undef STAGE_B

  // epilogue: f32 C-write to attn [T][S]
  const int r4 = (lane >> 4) * 4;
#pragma unroll
  for (int am = 0; am < 8; ++am) {
#pragma unroll
    for (int an = 0; an < 4; ++an) {
      const long gm = m0 + wr * 128 + am * 16 + r4;
      const int gn = n0 + wc * 64 + an * 16 + fr;
      float* po = outF + (long)bz * T_ * S_ + gm * (long)S_ + gn;
#pragma unroll
      for (int r = 0; r < 4; ++r) po[(long)r * S_] = acc[am][an][r];
    }
  }
}

// ---------- softmax over last dim (rows of 2048 f32), in place + fp16 copy out
__global__ __launch_bounds__(256) void softmax_kernel(float* __restrict__ a,
                                                      u16* __restrict__ ab) {
  const int tid = threadIdx.x;
  float* p = a + (long)blockIdx.x * 2048;
  u16* pb = ab + (long)blockIdx.x * 2048;
  f4 v0 = ((const f4*)p)[tid];
  f4 v1 = ((const f4*)p)[tid + 256];
  float m = fmaxf(fmaxf(fmaxf(v0[0], v0[1]), fmaxf(v0[2], v0[3])),
                  fmaxf(fmaxf(v1[0], v1[1]), fmaxf(v1[2], v1[3])));
#pragma unroll
  for (int o = 32; o >= 1; o >>= 1) m = fmaxf(m, __shfl_xor(m, o));
  __shared__ float redm[4], reds[4];
  if ((tid & 63) == 0) redm[tid >> 6] = m;
  __syncthreads();
  m = fmaxf(fmaxf(redm[0], redm[1]), fmaxf(redm[2], redm[3]));
  float s = 0.f;
#pragma unroll
  for (int j = 0; j < 4; ++j) { v0[j] = __expf(v0[j] - m); s += v0[j]; }
#pragma unroll
  for (int j = 0; j < 4; ++j) { v1[j] = __expf(v1[j] - m); s += v1[j]; }
#pragma unroll
  for (int o = 32; o >= 1; o >>= 1) s += __shfl_xor(s, o);
  if ((tid & 63) == 0) reds[tid >> 6] = s;
  __syncthreads();
  const float inv = 1.0f / (reds[0] + reds[1] + reds[2] + reds[3]);
  v0 *= inv; v1 *= inv;
  ((f4*)p)[tid] = v0;
  ((f4*)p)[tid + 256] = v1;
  u16x4 c0, c1;
#pragma unroll
  for (int j = 0; j < 4; ++j) { c0[j] = f2h(v0[j]); c1[j] = f2h(v1[j]); }
  ((u16x4*)pb)[tid] = c0;
  ((u16x4*)pb)[tid + 256] = c1;
}

extern "C" void kernel_launch(void* const* d_in, const int* in_sizes, int n_in,
                              void* d_out, int out_size, void* d_ws, size_t ws_size,
                              hipStream_t stream) {
  const float* base  = (const float*)d_in[0];
  const float* x     = (const float*)d_in[1];
  const float* enc_t = (const float*)d_in[2];
  const float* enc_c = (const float*)d_in[3];
  const float* W     = (const float*)d_in[4];
  const float* bias  = (const float*)d_in[5];

  float* ctx  = (float*)d_out;                       // [B,C,T]
  float* attn = ctx + (long)B_ * C_ * T_;            // [B,T,S]

  const long NBTC = (long)B_ * T_ * C_;              // 8388608
  u16* x_hi = (u16*)d_ws;           // bf16 [B,T,C]
  u16* x_lo = x_hi + NBTC;          // bf16
  u16* et_h = x_lo + NBTC;          // fp16 [B,S,C]
  u16* pad  = et_h + NBTC;          // (reserved: 4th quarter of attn_h alias)
  u16* ec_h = pad + NBTC;           // fp16 [B,C,S]
  u16* w_hi = ec_h + NBTC;          // bf16 [C,C]
  u16* w_lo = w_hi + (long)C_ * C_;

  // target fp16 hi/lo in d_out ctx region (2*NBTC u16 = exactly 32 MB, dead until GEMM3)
  u16* t_h = (u16*)d_out;
  u16* t_l = t_h + NBTC;
  // attn fp16 copy aliases x_hi,x_lo,et_h,pad (exactly 4*NBTC = B*T*S), all dead after GEMM2
  u16* attn_h = x_hi;

  dim3 tb(32, 8);
  // x [B,C,T] -> x_hi/x_lo bf16 [B,T,C]
  transpose_kernel<0><<<dim3(T_ / 32, C_ / 32, B_), tb, 0, stream>>>(x, x_hi, x_lo, T_);
  // enc_t [B,C,S] -> et_h fp16 [B,S,C]
  transpose_kernel<1><<<dim3(S_ / 32, C_ / 32, B_), tb, 0, stream>>>(enc_t, et_h, nullptr, S_);
  // enc_c -> ec_h fp16 (no transpose)
  split_kernel<1><<<2048, 256, 0, stream>>>(enc_c, ec_h, nullptr, (long)B_ * C_ * S_ / 4);
  // W -> w_hi/w_lo bf16
  split_kernel<0><<<256, 256, 0, stream>>>(W, w_hi, w_lo, (long)C_ * C_ / 4);

  // GEMM1 (3-pass bf16): target^T[t][o] = sum_c x^T[t][c]*W[o][c];
  // epilogue +base+bias, *scale, exact fp16 hi/lo split store
  gemm_kernel<3, 1, 0><<<dim3(C_ / 128, T_ / 128, B_), 256, 0, stream>>>(
      x_hi, x_lo, w_hi, w_lo,
      T_, C_, C_, (long)T_ * C_, 0L, (long)T_ * C_,
      base, bias, t_h, t_l, nullptr);

  // GEMM2 (256x256 8-phase fp16, 16 k-tiles: Th.E + Tl.E) -> attn f32
  gemm8p_kernel<<<dim3(S_ / 256, T_ / 256, B_), 512, 0, stream>>>(
      t_h, t_l, et_h, attn);

  // softmax rows in place + fp16 copy
  softmax_kernel<<<B_ * T_, 256, 0, stream>>>(attn, attn_h);

  // GEMM3 (1-pass fp16): ctx[c][t] = sum_s ec[c][s] * attn_h[t][s]
  gemm_kernel<1, 0, 1><<<dim3(T_ / 128, C_ / 128, B_), 256, 0, stream>>>(
      ec_h, nullptr, attn_h, nullptr,
      C_, T_, S_, (long)C_ * S_, (long)T_ * S_, (long)C_ * T_,
      nullptr, nullptr, nullptr, nullptr, ctx);

  (void)in_sizes; (void)n_in; (void)out_size; (void)ws_size;
}

// Round 9
// 263.691 us; speedup vs baseline: 1.2414x; 1.0255x over previous
//
#include <hip/hip_runtime.h>

typedef unsigned short u16;
typedef __attribute__((ext_vector_type(4))) float f4;
typedef __attribute__((ext_vector_type(8))) short bf8;
typedef __attribute__((ext_vector_type(8))) _Float16 h8;
typedef __attribute__((ext_vector_type(4))) unsigned short u16x4;

#define B_ 8
#define C_ 512
#define T_ 2048
#define S_ 2048
#define SCALE_W 0.70710678118654752440f

__device__ __forceinline__ u16 f2h(float f) {
  return __builtin_bit_cast(u16, (_Float16)f);
}
__device__ __forceinline__ float h2f(u16 h) {
  return (float)__builtin_bit_cast(_Float16, h);
}

__device__ __forceinline__ void gload16(const u16* g, u16* l) {
  __builtin_amdgcn_global_load_lds((__attribute__((address_space(1))) const void*)g,
                                   (__attribute__((address_space(3))) void*)l, 16, 0, 0);
}

#define MEMF() asm volatile("" ::: "memory")
#define BAR()  do { MEMF(); __builtin_amdgcn_s_barrier(); MEMF(); } while (0)
#define LGKM0() do { asm volatile("s_waitcnt lgkmcnt(0)" ::: "memory"); \
                     __builtin_amdgcn_sched_barrier(0); } while (0)

// ---------- prep: transpose [B,C,X] -> [B,X,C], fp16 single
__global__ __launch_bounds__(256) void transpose_kernel(
    const float* __restrict__ in, u16* __restrict__ oh, int X)
{
  __shared__ float t[32][33];
  const int tx = threadIdx.x, ty = threadIdx.y;
  const long cbase = (long)blockIdx.z * C_ + blockIdx.y * 32;
  const long xbase = (long)blockIdx.x * 32;
  const float* ip = in + cbase * X + xbase;
#pragma unroll
  for (int i = 0; i < 4; ++i)
    t[ty + i * 8][tx] = ip[(long)(ty + i * 8) * X + tx];
  __syncthreads();
  const long obase = ((long)blockIdx.z * X + xbase) * C_ + blockIdx.y * 32;
#pragma unroll
  for (int i = 0; i < 4; ++i)
    oh[obase + (long)(ty + i * 8) * C_ + tx] = f2h(t[tx][ty + i * 8]);
}

// ---------- prep: elementwise f32 -> fp16. LO=1: exact hi/lo split pair.
template<int LO>
__global__ __launch_bounds__(256) void split_kernel(
    const float* __restrict__ in, u16* __restrict__ oh, u16* __restrict__ ol, long n4)
{
  long i = (long)blockIdx.x * 256 + threadIdx.x;
  const long stride = (long)gridDim.x * 256;
  for (; i < n4; i += stride) {
    f4 v = ((const f4*)in)[i];
    u16x4 hv, lv;
#pragma unroll
    for (int j = 0; j < 4; ++j) {
      u16 h = f2h(v[j]);
      hv[j] = h;
      if (LO) lv[j] = f2h(v[j] - h2f(h));
    }
    ((u16x4*)oh)[i] = hv;
    if (LO) ((u16x4*)ol)[i] = lv;
  }
}

// ---------- GEMM1 (128x128, BK=32, fp16 2-pass, W exact-split):
// t[t][o] = (sum_c x[t][c]*(Wh+Wl)[o][c] + base[o][t] + bias[o]) * SCALE, fp16 hi/lo store
__global__ __launch_bounds__(256, 2) void gemm1_kernel(
    const u16* __restrict__ A,
    const u16* __restrict__ Bh, const u16* __restrict__ Bl,
    const float* __restrict__ baseO, const float* __restrict__ bias,
    u16* __restrict__ outH, u16* __restrict__ outL)
{
  constexpr int BM = 128, BK = 32, K = C_, N = C_;
  constexpr int TILE = BM * BK;
  __shared__ u16 lA[TILE], lBh[TILE], lBl[TILE];

  const int tid = threadIdx.x;
  const int wid = tid >> 6;
  const int lane = tid & 63;
  const int wr = wid >> 1, wc = wid & 1;
  const int bz = blockIdx.z;
  const int m0 = blockIdx.y * BM;
  const int n0 = blockIdx.x * BM;

  const u16* gA  = A + ((long)bz * T_ + m0) * K;
  const u16* gBh = Bh + (long)n0 * K;
  const u16* gBl = Bl + (long)n0 * K;

  const int srow = tid >> 2;
  const int skoff = (tid & 3) * 8;
  const int ldsOff = wid * 512;

  f4 acc[4][4] = {};

  for (int k0 = 0; k0 < K; k0 += BK) {
    __syncthreads();
#pragma unroll
    for (int c = 0; c < 2; ++c) {
      const long go = (long)(c * 64 + srow) * K + k0 + skoff;
      const int lo = c * 2048 + ldsOff;
      gload16(gA + go, lA + lo);
      gload16(gBh + go, lBh + lo);
      gload16(gBl + go, lBl + lo);
    }
    asm volatile("s_waitcnt vmcnt(0)" ::: "memory");
    __syncthreads();

    bf8 a_[4], b_h[4], b_l[4];
    const int fr = lane & 15;
    const int fk = (lane >> 4) * 8;
#pragma unroll
    for (int i = 0; i < 4; ++i) {
      a_[i]  = *(const bf8*)&lA[(wr * 64 + i * 16 + fr) * BK + fk];
      b_h[i] = *(const bf8*)&lBh[(wc * 64 + i * 16 + fr) * BK + fk];
      b_l[i] = *(const bf8*)&lBl[(wc * 64 + i * 16 + fr) * BK + fk];
    }
#pragma unroll
    for (int mi = 0; mi < 4; ++mi)
#pragma unroll
      for (int ni = 0; ni < 4; ++ni) {
        acc[mi][ni] = __builtin_amdgcn_mfma_f32_16x16x32_f16(
            __builtin_bit_cast(h8, a_[mi]), __builtin_bit_cast(h8, b_h[ni]),
            acc[mi][ni], 0, 0, 0);
        acc[mi][ni] = __builtin_amdgcn_mfma_f32_16x16x32_f16(
            __builtin_bit_cast(h8, a_[mi]), __builtin_bit_cast(h8, b_l[ni]),
            acc[mi][ni], 0, 0, 0);
      }
  }

  const int fr = lane & 15;
  const int r4 = (lane >> 4) * 4;
#pragma unroll
  for (int mi = 0; mi < 4; ++mi) {
#pragma unroll
    for (int ni = 0; ni < 4; ++ni) {
      const int gn = n0 + wc * 64 + ni * 16 + fr;
      const long gmb = m0 + wr * 64 + mi * 16 + r4;
      // base in original [B][C][T] layout: channel gn, t = gmb..gmb+3 (f4 aligned)
      f4 bv = *(const f4*)(baseO + ((long)bz * C_ + gn) * T_ + gmb);
      const float bs = bias[gn];
#pragma unroll
      for (int r = 0; r < 4; ++r) {
        float val = (acc[mi][ni][r] + bv[r] + bs) * SCALE_W;
        const long idx = ((long)bz * T_ + gmb + r) * (long)N + gn;
        u16 h = f2h(val);
        outH[idx] = h;
        outL[idx] = f2h(val - h2f(h));
      }
    }
  }
}

// ---------- 256x256 / BK=64 / 8-wave phase-pipelined fp16 GEMM (counted vmcnt)
// LDS slot swizzle (proven conflict-free, round 7): store LDS[R][slot ^ (R&7)].
// out[M][N] = sum over NT k-tiles of 64; A source switches at tile TPP (2-pass),
// B cycles every TPP tiles. LDK = K-stride of both operands' rows.
template<int NT, int TPP, int LDK>
__device__ __forceinline__ void stage2(const u16* g, u16* l) {
  gload16(g, l);
  gload16(g + 64 * LDK, l + 4096);   // +64 rows: (row+64)&7 unchanged -> same swizzle
}
template<int NF>
__device__ __forceinline__ void rd_frags(bf8 (&d)[NF][2], const u16* p, int k0o, int k1o) {
#pragma unroll
  for (int i = 0; i < NF; ++i) {
    d[i][0] = *(const bf8*)&p[i * 1024 + k0o];
    d[i][1] = *(const bf8*)&p[i * 1024 + k1o];
  }
}
template<int MH, int NH>
__device__ __forceinline__ void mmq(f4 (&acc)[8][4], const bf8 (&a)[4][2], const bf8 (&b)[2][2]) {
  __builtin_amdgcn_s_setprio(1);
#pragma unroll
  for (int mi = 0; mi < 4; ++mi)
#pragma unroll
    for (int ni = 0; ni < 2; ++ni)
#pragma unroll
      for (int ks = 0; ks < 2; ++ks)
        acc[MH * 4 + mi][NH * 2 + ni] = __builtin_amdgcn_mfma_f32_16x16x32_f16(
            __builtin_bit_cast(h8, a[mi][ks]), __builtin_bit_cast(h8, b[ni][ks]),
            acc[MH * 4 + mi][NH * 2 + ni], 0, 0, 0);
  __builtin_amdgcn_s_setprio(0);
}

template<int NT, int TPP, int LDK>
__global__ __launch_bounds__(512, 2) void gemm8p_kernel(
    const u16* __restrict__ A0, const u16* __restrict__ A1,
    const u16* __restrict__ B0,
    float* __restrict__ outF,
    long sA, long sB, long sO, int Nr)
{
  __shared__ u16 lds[65536];  // A: [2buf][256r][64c] @0 ; B: same @32768 (u16 units)
  const int tid = threadIdx.x;
  const int wid = tid >> 6, lane = tid & 63;
  const int wr = wid >> 2, wc = wid & 3;

  // bijective XCD swizzle (nwg divisible by 8 for all our launches)
  const int gx = gridDim.x, gy = gridDim.y;
  int lin = blockIdx.x + gx * (blockIdx.y + gy * blockIdx.z);
  const int nwg = gx * gy * (int)gridDim.z;
  lin = (lin & 7) * (nwg >> 3) + (lin >> 3);
  const int bx = lin % gx;
  const int tmp = lin / gx;
  const int by = tmp % gy, bz = tmp / gy;

  const int m0 = by * 256, n0 = bx * 256;
  const u16* gA0 = A0 + (long)bz * sA + (long)m0 * LDK;
  const u16* gA1 = A1 + (long)bz * sA + (long)m0 * LDK;
  const u16* gB  = B0 + (long)bz * sB + (long)n0 * LDK;

  // staging geometry: per half-tile (128 rows x 64 u16 cols), 2 gloads/thread.
  // LDS dest linear (slot = tid&7); source slot = (tid&7) ^ (srow&7).
  const int srow = tid >> 3;                                   // 0..63
  const int scol = (((tid & 7) ^ (srow & 7)) * 8);             // u16
  const int dstA = tid * 8;                                    // u16

  // fragment-read: nominal slot = ks*4 + g; swizzled col = ((ks*4+g) ^ (lane&7))*8
  const int fr = lane & 15;
  const int k0o = (((lane >> 4) ^ (lane & 7)) * 8);            // ks=0
  const int k1o = k0o ^ 32;                                    // ks=1 (slot bit 2)
  const int abase = (wr * 128 + fr) * 64;
  const int bbase = 32768 + (wc * 64 + fr) * 64;

  f4 acc[8][4] = {};

#define SRC_A(tt) ((((tt) / TPP) == 0 ? gA0 : gA1) + ((tt) % TPP) * 64)
#define SRC_B(tt) (gB + ((tt) % TPP) * 64)
#define STAGE_A(tt, h) stage2<NT, TPP, LDK>(SRC_A(tt) + (long)((h) * 128 + srow) * LDK + scol, \
                              lds + (((tt) & 1) * 16384 + (h) * 8192 + dstA))
#define STAGE_B(tt, h) stage2<NT, TPP, LDK>(SRC_B(tt) + (long)((h) * 128 + srow) * LDK + scol, \
                              lds + (32768 + ((tt) & 1) * 16384 + (h) * 8192 + dstA))

  // prologue: tile0 fully + B(1,0) (10 loads in flight)
  STAGE_B(0, 0); STAGE_B(0, 1); STAGE_A(0, 0); STAGE_A(0, 1); STAGE_B(1, 0);
  asm volatile("s_waitcnt vmcnt(2)" ::: "memory");  // tile0 landed; B(1)h0 may fly
  BAR();

  bf8 af[4][2], b0[2][2], b1[2][2];
  for (int kt = 0; kt < NT - 1; ++kt) {
    const int cur = kt & 1;
    const u16* la = lds + cur * 16384 + abase;
    const u16* lb = lds + cur * 16384 + bbase;
    // ---- ph1: Q(0,0)
    rd_frags(af, la, k0o, k1o);
    rd_frags(b0, lb, k0o, k1o);
    STAGE_B(kt + 1, 1);
    BAR(); LGKM0();
    mmq<0, 0>(acc, af, b0);
    BAR();
    // ---- ph2: Q(0,1)
    rd_frags(b1, lb + 2048, k0o, k1o);
    STAGE_A(kt + 1, 0);
    BAR(); LGKM0();
    mmq<0, 1>(acc, af, b1);
    BAR();
    // ---- ph3: Q(1,0)
    rd_frags(af, la + 4096, k0o, k1o);
    STAGE_A(kt + 1, 1);
    BAR(); LGKM0();
    mmq<1, 0>(acc, af, b0);
    BAR();
    // ---- ph4: Q(1,1)
    {
      int t2 = kt + 2; if (t2 > NT - 1) t2 = NT - 1;  // harmless duplicate re-stage at tail
      STAGE_B(t2, 0);
    }
    BAR();
    mmq<1, 1>(acc, af, b1);
    if (kt == NT - 2) { asm volatile("s_waitcnt vmcnt(0)" ::: "memory"); }
    else             { asm volatile("s_waitcnt vmcnt(2)" ::: "memory"); }
    BAR();
  }
  // peeled final tile (no staging)
  {
    const int cur = (NT - 1) & 1;
    const u16* la = lds + cur * 16384 + abase;
    const u16* lb = lds + cur * 16384 + bbase;
    rd_frags(af, la, k0o, k1o);
    rd_frags(b0, lb, k0o, k1o);
    BAR(); LGKM0();
    mmq<0, 0>(acc, af, b0);
    BAR();
    rd_frags(b1, lb + 2048, k0o, k1o);
    BAR(); LGKM0();
    mmq<0, 1>(acc, af, b1);
    BAR();
    rd_frags(af, la + 4096, k0o, k1o);
    BAR(); LGKM0();
    mmq<1, 0>(acc, af, b0);
    BAR();
    mmq<1, 1>(acc, af, b1);
  }
#undef SRC_A
#undef SRC_B
#undef STAGE_A
#undef STAGE_B

  // epilogue: f32 C-write
  const int r4 = (lane >> 4) * 4;
#pragma unroll
  for (int am = 0; am < 8; ++am) {
#pragma unroll
    for (int an = 0; an < 4; ++an) {
      const long gm = m0 + wr * 128 + am * 16 + r4;
      const int gn = n0 + wc * 64 + an * 16 + fr;
      float* po = outF + (long)bz * sO + gm * (long)Nr + gn;
#pragma unroll
      for (int r = 0; r < 4; ++r) po[(long)r * Nr] = acc[am][an][r];
    }
  }
}

// ---------- softmax over last dim (rows of 2048 f32), in place + fp16 copy out
__global__ __launch_bounds__(256) void softmax_kernel(float* __restrict__ a,
                                                      u16* __restrict__ ab) {
  const int tid = threadIdx.x;
  float* p = a + (long)blockIdx.x * 2048;
  u16* pb = ab + (long)blockIdx.x * 2048;
  f4 v0 = ((const f4*)p)[tid];
  f4 v1 = ((const f4*)p)[tid + 256];
  float m = fmaxf(fmaxf(fmaxf(v0[0], v0[1]), fmaxf(v0[2], v0[3])),
                  fmaxf(fmaxf(v1[0], v1[1]), fmaxf(v1[2], v1[3])));
#pragma unroll
  for (int o = 32; o >= 1; o >>= 1) m = fmaxf(m, __shfl_xor(m, o));
  __shared__ float redm[4], reds[4];
  if ((tid & 63) == 0) redm[tid >> 6] = m;
  __syncthreads();
  m = fmaxf(fmaxf(redm[0], redm[1]), fmaxf(redm[2], redm[3]));
  float s = 0.f;
#pragma unroll
  for (int j = 0; j < 4; ++j) { v0[j] = __expf(v0[j] - m); s += v0[j]; }
#pragma unroll
  for (int j = 0; j < 4; ++j) { v1[j] = __expf(v1[j] - m); s += v1[j]; }
#pragma unroll
  for (int o = 32; o >= 1; o >>= 1) s += __shfl_xor(s, o);
  if ((tid & 63) == 0) reds[tid >> 6] = s;
  __syncthreads();
  const float inv = 1.0f / (reds[0] + reds[1] + reds[2] + reds[3]);
  v0 *= inv; v1 *= inv;
  ((f4*)p)[tid] = v0;
  ((f4*)p)[tid + 256] = v1;
  u16x4 c0, c1;
#pragma unroll
  for (int j = 0; j < 4; ++j) { c0[j] = f2h(v0[j]); c1[j] = f2h(v1[j]); }
  ((u16x4*)pb)[tid] = c0;
  ((u16x4*)pb)[tid + 256] = c1;
}

extern "C" void kernel_launch(void* const* d_in, const int* in_sizes, int n_in,
                              void* d_out, int out_size, void* d_ws, size_t ws_size,
                              hipStream_t stream) {
  const float* base  = (const float*)d_in[0];
  const float* x     = (const float*)d_in[1];
  const float* enc_t = (const float*)d_in[2];
  const float* enc_c = (const float*)d_in[3];
  const float* W     = (const float*)d_in[4];
  const float* bias  = (const float*)d_in[5];

  float* ctx  = (float*)d_out;                       // [B,C,T]
  float* attn = ctx + (long)B_ * C_ * T_;            // [B,T,S]

  const long NBTC = (long)B_ * T_ * C_;              // 8388608
  u16* x_h  = (u16*)d_ws;           // fp16 [B,T,C]   (quarter 0)
  u16* et_h = x_h + NBTC;           // fp16 [B,S,C]   (quarter 1)
  // quarters 2,3 free; attn_h aliases quarters 0..3 after GEMM2
  u16* ec_h = x_h + 4 * NBTC;       // fp16 [B,C,S]
  u16* w_h  = ec_h + NBTC;          // fp16 [C,C]
  u16* w_l  = w_h + (long)C_ * C_;  // fp16 [C,C] (exact residual)

  // target fp16 hi/lo in d_out ctx region (2*NBTC u16 = exactly 32 MB, dead until GEMM3)
  u16* t_h = (u16*)d_out;
  u16* t_l = t_h + NBTC;
  u16* attn_h = x_h;                // 4*NBTC u16 = exactly B*T*S

  dim3 tb(32, 8);
  // x [B,C,T] -> x_h fp16 [B,T,C]
  transpose_kernel<<<dim3(T_ / 32, C_ / 32, B_), tb, 0, stream>>>(x, x_h, T_);
  // enc_t [B,C,S] -> et_h fp16 [B,S,C]
  transpose_kernel<<<dim3(S_ / 32, C_ / 32, B_), tb, 0, stream>>>(enc_t, et_h, S_);
  // enc_c -> ec_h fp16 (no transpose)
  split_kernel<0><<<2048, 256, 0, stream>>>(enc_c, ec_h, nullptr, (long)B_ * C_ * S_ / 4);
  // W -> w_h + w_l (exact fp16 split)
  split_kernel<1><<<256, 256, 0, stream>>>(W, w_h, w_l, (long)C_ * C_ / 4);

  // GEMM1 (fp16 2-pass, W split exact): target + epilogue -> t_h/t_l
  gemm1_kernel<<<dim3(C_ / 128, T_ / 128, B_), 256, 0, stream>>>(
      x_h, w_h, w_l, base, bias, t_h, t_l);

  // GEMM2 (256x256 8-phase fp16, 16 k-tiles: Th.E + Tl.E) -> attn f32
  gemm8p_kernel<16, 8, 512><<<dim3(S_ / 256, T_ / 256, B_), 512, 0, stream>>>(
      t_h, t_l, et_h, attn,
      (long)T_ * C_, (long)S_ * C_, (long)T_ * S_, S_);

  // softmax rows in place + fp16 copy
  softmax_kernel<<<B_ * T_, 256, 0, stream>>>(attn, attn_h);

  // GEMM3 (256x256 8-phase fp16, 32 k-tiles, 1 pass): ctx[c][t] = sum_s ec[c][s]*attn_h[t][s]
  gemm8p_kernel<32, 32, 2048><<<dim3(T_ / 256, C_ / 256, B_), 512, 0, stream>>>(
      ec_h, ec_h, attn_h, ctx,
      (long)C_ * S_, (long)T_ * S_, (long)C_ * T_, T_);

  (void)in_sizes; (void)n_in; (void)out_size; (void)ws_size;
}

// Round 10
// 244.199 us; speedup vs baseline: 1.3404x; 1.0798x over previous
//
#include <hip/hip_runtime.h>

typedef unsigned short u16;
typedef __attribute__((ext_vector_type(4))) float f4;
typedef __attribute__((ext_vector_type(8))) short bf8;
typedef __attribute__((ext_vector_type(8))) _Float16 h8;
typedef __attribute__((ext_vector_type(4))) unsigned short u16x4;

#define B_ 8
#define C_ 512
#define T_ 2048
#define S_ 2048
#define SCALE_W 0.70710678118654752440f

__device__ __forceinline__ u16 f2h(float f) {
  return __builtin_bit_cast(u16, (_Float16)f);
}
__device__ __forceinline__ float h2f(u16 h) {
  return (float)__builtin_bit_cast(_Float16, h);
}

__device__ __forceinline__ void gload16(const u16* g, u16* l) {
  __builtin_amdgcn_global_load_lds((__attribute__((address_space(1))) const void*)g,
                                   (__attribute__((address_space(3))) void*)l, 16, 0, 0);
}

#define MEMF() asm volatile("" ::: "memory")
#define BAR()  do { MEMF(); __builtin_amdgcn_s_barrier(); MEMF(); } while (0)
#define LGKM0() do { asm volatile("s_waitcnt lgkmcnt(0)" ::: "memory"); \
                     __builtin_amdgcn_sched_barrier(0); } while (0)

// ---------- prep: transpose [B,C,X] -> [B,X,C], fp16 single
__global__ __launch_bounds__(256) void transpose_kernel(
    const float* __restrict__ in, u16* __restrict__ oh, int X)
{
  __shared__ float t[32][33];
  const int tx = threadIdx.x, ty = threadIdx.y;
  const long cbase = (long)blockIdx.z * C_ + blockIdx.y * 32;
  const long xbase = (long)blockIdx.x * 32;
  const float* ip = in + cbase * X + xbase;
#pragma unroll
  for (int i = 0; i < 4; ++i)
    t[ty + i * 8][tx] = ip[(long)(ty + i * 8) * X + tx];
  __syncthreads();
  const long obase = ((long)blockIdx.z * X + xbase) * C_ + blockIdx.y * 32;
#pragma unroll
  for (int i = 0; i < 4; ++i)
    oh[obase + (long)(ty + i * 8) * C_ + tx] = f2h(t[tx][ty + i * 8]);
}

// ---------- prep: elementwise f32 -> fp16. LO=1: exact hi/lo split pair.
template<int LO>
__global__ __launch_bounds__(256) void split_kernel(
    const float* __restrict__ in, u16* __restrict__ oh, u16* __restrict__ ol, long n4)
{
  long i = (long)blockIdx.x * 256 + threadIdx.x;
  const long stride = (long)gridDim.x * 256;
  for (; i < n4; i += stride) {
    f4 v = ((const f4*)in)[i];
    u16x4 hv, lv;
#pragma unroll
    for (int j = 0; j < 4; ++j) {
      u16 h = f2h(v[j]);
      hv[j] = h;
      if (LO) lv[j] = f2h(v[j] - h2f(h));
    }
    ((u16x4*)oh)[i] = hv;
    if (LO) ((u16x4*)ol)[i] = lv;
  }
}

// ---------- GEMM1 (128x128, BK=32, fp16 2-pass, W exact-split):
// t[t][o] = (sum_c x[t][c]*(Wh+Wl)[o][c] + base[o][t] + bias[o]) * SCALE, fp16 hi/lo store
__global__ __launch_bounds__(256, 2) void gemm1_kernel(
    const u16* __restrict__ A,
    const u16* __restrict__ Bh, const u16* __restrict__ Bl,
    const float* __restrict__ baseO, const float* __restrict__ bias,
    u16* __restrict__ outH, u16* __restrict__ outL)
{
  constexpr int BM = 128, BK = 32, K = C_, N = C_;
  constexpr int TILE = BM * BK;
  __shared__ u16 lA[TILE], lBh[TILE], lBl[TILE];

  const int tid = threadIdx.x;
  const int wid = tid >> 6;
  const int lane = tid & 63;
  const int wr = wid >> 1, wc = wid & 1;
  const int bz = blockIdx.z;
  const int m0 = blockIdx.y * BM;
  const int n0 = blockIdx.x * BM;

  const u16* gA  = A + ((long)bz * T_ + m0) * K;
  const u16* gBh = Bh + (long)n0 * K;
  const u16* gBl = Bl + (long)n0 * K;

  const int srow = tid >> 2;
  const int skoff = (tid & 3) * 8;
  const int ldsOff = wid * 512;

  f4 acc[4][4] = {};

  for (int k0 = 0; k0 < K; k0 += BK) {
    __syncthreads();
#pragma unroll
    for (int c = 0; c < 2; ++c) {
      const long go = (long)(c * 64 + srow) * K + k0 + skoff;
      const int lo = c * 2048 + ldsOff;
      gload16(gA + go, lA + lo);
      gload16(gBh + go, lBh + lo);
      gload16(gBl + go, lBl + lo);
    }
    asm volatile("s_waitcnt vmcnt(0)" ::: "memory");
    __syncthreads();

    bf8 a_[4], b_h[4], b_l[4];
    const int fr = lane & 15;
    const int fk = (lane >> 4) * 8;
#pragma unroll
    for (int i = 0; i < 4; ++i) {
      a_[i]  = *(const bf8*)&lA[(wr * 64 + i * 16 + fr) * BK + fk];
      b_h[i] = *(const bf8*)&lBh[(wc * 64 + i * 16 + fr) * BK + fk];
      b_l[i] = *(const bf8*)&lBl[(wc * 64 + i * 16 + fr) * BK + fk];
    }
#pragma unroll
    for (int mi = 0; mi < 4; ++mi)
#pragma unroll
      for (int ni = 0; ni < 4; ++ni) {
        acc[mi][ni] = __builtin_amdgcn_mfma_f32_16x16x32_f16(
            __builtin_bit_cast(h8, a_[mi]), __builtin_bit_cast(h8, b_h[ni]),
            acc[mi][ni], 0, 0, 0);
        acc[mi][ni] = __builtin_amdgcn_mfma_f32_16x16x32_f16(
            __builtin_bit_cast(h8, a_[mi]), __builtin_bit_cast(h8, b_l[ni]),
            acc[mi][ni], 0, 0, 0);
      }
  }

  const int fr = lane & 15;
  const int r4 = (lane >> 4) * 4;
#pragma unroll
  for (int mi = 0; mi < 4; ++mi) {
#pragma unroll
    for (int ni = 0; ni < 4; ++ni) {
      const int gn = n0 + wc * 64 + ni * 16 + fr;
      const long gmb = m0 + wr * 64 + mi * 16 + r4;
      // base in original [B][C][T] layout: channel gn, t = gmb..gmb+3 (f4 aligned)
      f4 bv = *(const f4*)(baseO + ((long)bz * C_ + gn) * T_ + gmb);
      const float bs = bias[gn];
#pragma unroll
      for (int r = 0; r < 4; ++r) {
        float val = (acc[mi][ni][r] + bv[r] + bs) * SCALE_W;
        const long idx = ((long)bz * T_ + gmb + r) * (long)N + gn;
        u16 h = f2h(val);
        outH[idx] = h;
        outL[idx] = f2h(val - h2f(h));
      }
    }
  }
}

// ---------- 256-col / BK=64 / 8-wave phase-pipelined fp16 GEMM (counted vmcnt)
// MF = A-fragments per wave-half: MF=4 -> BM=256 (identical to proven round-7/8 kernel),
// MF=2 -> BM=128 (full occupancy for small-M GEMMs). Ledger holds for both:
// per K-tile A issues MF loads (2 halves x MF/2), B issues 4; vmcnt(2) at ph4-tail
// leaves exactly B(kt+2,0)'s 2 loads in flight; tile kt+1 fully landed.
// LDS slot swizzle (proven conflict-free, round 7): store LDS[R][slot ^ (R&7)].
template<int MF, int LDK>
__device__ __forceinline__ void stage_a(const u16* g, u16* l) {
  gload16(g, l);
  if (MF == 4) gload16(g + 64 * LDK, l + 4096);  // +64 rows: same &7 -> same swizzle
}
template<int LDK>
__device__ __forceinline__ void stage_b(const u16* g, u16* l) {
  gload16(g, l);
  gload16(g + 64 * LDK, l + 4096);
}
template<int NF>
__device__ __forceinline__ void rd_frags(bf8 (&d)[NF][2], const u16* p, int k0o, int k1o) {
#pragma unroll
  for (int i = 0; i < NF; ++i) {
    d[i][0] = *(const bf8*)&p[i * 1024 + k0o];
    d[i][1] = *(const bf8*)&p[i * 1024 + k1o];
  }
}
template<int MH, int NH, int MF>
__device__ __forceinline__ void mmq(f4 (&acc)[2 * MF][4], const bf8 (&a)[MF][2],
                                    const bf8 (&b)[2][2]) {
  __builtin_amdgcn_s_setprio(1);
#pragma unroll
  for (int mi = 0; mi < MF; ++mi)
#pragma unroll
    for (int ni = 0; ni < 2; ++ni)
#pragma unroll
      for (int ks = 0; ks < 2; ++ks)
        acc[MH * MF + mi][NH * 2 + ni] = __builtin_amdgcn_mfma_f32_16x16x32_f16(
            __builtin_bit_cast(h8, a[mi][ks]), __builtin_bit_cast(h8, b[ni][ks]),
            acc[MH * MF + mi][NH * 2 + ni], 0, 0, 0);
  __builtin_amdgcn_s_setprio(0);
}

template<int NT, int TPP, int LDK, int MF, int OUT16>
__global__ __launch_bounds__(512, 2) void gemm8p_kernel(
    const u16* __restrict__ A0, const u16* __restrict__ A1,
    const u16* __restrict__ B0,
    void* __restrict__ outP,
    long sA, long sB, long sO, int Nr)
{
  // A: [2buf][BM][64] @0 (BM = MF*64); B: [2buf][256][64] @ MF*8192 (u16 units)
  __shared__ u16 lds[MF * 8192 + 32768];
  const int tid = threadIdx.x;
  const int wid = tid >> 6, lane = tid & 63;
  const int wr = wid >> 2, wc = wid & 3;

  // bijective XCD swizzle (nwg divisible by 8 for all our launches)
  const int gx = gridDim.x, gy = gridDim.y;
  int lin = blockIdx.x + gx * (blockIdx.y + gy * blockIdx.z);
  const int nwg = gx * gy * (int)gridDim.z;
  lin = (lin & 7) * (nwg >> 3) + (lin >> 3);
  const int bx = lin % gx;
  const int tmp = lin / gx;
  const int by = tmp % gy, bz = tmp / gy;

  const int m0 = by * (MF * 64), n0 = bx * 256;
  const u16* gA0 = A0 + (long)bz * sA + (long)m0 * LDK;
  const u16* gA1 = A1 + (long)bz * sA + (long)m0 * LDK;
  const u16* gB  = B0 + (long)bz * sB + (long)n0 * LDK;

  // staging: LDS dest linear (slot = tid&7); source slot = (tid&7) ^ (srow&7)
  const int srow = tid >> 3;                                   // 0..63
  const int scol = (((tid & 7) ^ (srow & 7)) * 8);             // u16
  const int dstA = tid * 8;                                    // u16

  // fragment-read: nominal slot = ks*4 + g; swizzled col = ((ks*4+g) ^ (lane&7))*8
  const int fr = lane & 15;
  const int k0o = (((lane >> 4) ^ (lane & 7)) * 8);            // ks=0
  const int k1o = k0o ^ 32;                                    // ks=1 (slot bit 2)
  const int abase = (wr * (MF * 32) + fr) * 64;
  const int bbase = MF * 8192 + (wc * 64 + fr) * 64;

  f4 acc[2 * MF][4] = {};

#define SRC_A(tt) ((((tt) / TPP) == 0 ? gA0 : gA1) + ((tt) % TPP) * 64)
#define SRC_B(tt) (gB + ((tt) % TPP) * 64)
#define STAGE_A(tt, h) stage_a<MF, LDK>( \
    SRC_A(tt) + (long)((h) * (MF * 32) + srow) * LDK + scol, \
    lds + (((tt) & 1) * (MF * 4096) + (h) * (MF * 2048) + dstA))
#define STAGE_B(tt, h) stage_b<LDK>( \
    SRC_B(tt) + (long)((h) * 128 + srow) * LDK + scol, \
    lds + (MF * 8192 + ((tt) & 1) * 16384 + (h) * 8192 + dstA))

  // prologue: tile0 fully + B(1,0)
  STAGE_B(0, 0); STAGE_B(0, 1); STAGE_A(0, 0); STAGE_A(0, 1); STAGE_B(1, 0);
  asm volatile("s_waitcnt vmcnt(2)" ::: "memory");  // tile0 landed; B(1)h0 may fly
  BAR();

  bf8 af[MF][2], b0[2][2], b1[2][2];
  for (int kt = 0; kt < NT - 1; ++kt) {
    const int cur = kt & 1;
    const u16* la = lds + cur * (MF * 4096) + abase;
    const u16* lb = lds + cur * 16384 + bbase;
    // ---- ph1: Q(0,0)
    rd_frags(af, la, k0o, k1o);
    rd_frags(b0, lb, k0o, k1o);
    STAGE_B(kt + 1, 1);
    BAR(); LGKM0();
    mmq<0, 0, MF>(acc, af, b0);
    BAR();
    // ---- ph2: Q(0,1)
    rd_frags(b1, lb + 2048, k0o, k1o);
    STAGE_A(kt + 1, 0);
    BAR(); LGKM0();
    mmq<0, 1, MF>(acc, af, b1);
    BAR();
    // ---- ph3: Q(1,0)
    rd_frags(af, la + MF * 1024, k0o, k1o);
    STAGE_A(kt + 1, 1);
    BAR(); LGKM0();
    mmq<1, 0, MF>(acc, af, b0);
    BAR();
    // ---- ph4: Q(1,1)
    {
      int t2 = kt + 2; if (t2 > NT - 1) t2 = NT - 1;  // harmless duplicate re-stage at tail
      STAGE_B(t2, 0);
    }
    BAR();
    mmq<1, 1, MF>(acc, af, b1);
    if (kt == NT - 2) { asm volatile("s_waitcnt vmcnt(0)" ::: "memory"); }
    else             { asm volatile("s_waitcnt vmcnt(2)" ::: "memory"); }
    BAR();
  }
  // peeled final tile (no staging)
  {
    const int cur = (NT - 1) & 1;
    const u16* la = lds + cur * (MF * 4096) + abase;
    const u16* lb = lds + cur * 16384 + bbase;
    rd_frags(af, la, k0o, k1o);
    rd_frags(b0, lb, k0o, k1o);
    BAR(); LGKM0();
    mmq<0, 0, MF>(acc, af, b0);
    BAR();
    rd_frags(b1, lb + 2048, k0o, k1o);
    BAR(); LGKM0();
    mmq<0, 1, MF>(acc, af, b1);
    BAR();
    rd_frags(af, la + MF * 1024, k0o, k1o);
    BAR(); LGKM0();
    mmq<1, 0, MF>(acc, af, b0);
    BAR();
    mmq<1, 1, MF>(acc, af, b1);
  }
#undef SRC_A
#undef SRC_B
#undef STAGE_A
#undef STAGE_B

  // epilogue: C-write (f32 or fp16)
  const int r4 = (lane >> 4) * 4;
#pragma unroll
  for (int am = 0; am < 2 * MF; ++am) {
#pragma unroll
    for (int an = 0; an < 4; ++an) {
      const long gm = m0 + wr * (MF * 32) + am * 16 + r4;
      const int gn = n0 + wc * 64 + an * 16 + fr;
      if (OUT16) {
        u16* po = (u16*)outP + (long)bz * sO + gm * (long)Nr + gn;
#pragma unroll
        for (int r = 0; r < 4; ++r) po[(long)r * Nr] = f2h(acc[am][an][r]);
      } else {
        float* po = (float*)outP + (long)bz * sO + gm * (long)Nr + gn;
#pragma unroll
        for (int r = 0; r < 4; ++r) po[(long)r * Nr] = acc[am][an][r];
      }
    }
  }
}

// ---------- softmax: read fp16 pre_a row, write f32 attn (d_out) + fp16 back in place
__global__ __launch_bounds__(256) void softmax_kernel(u16* __restrict__ pah,
                                                      float* __restrict__ aout) {
  const int tid = threadIdx.x;
  u16* ph = pah + (long)blockIdx.x * 2048;
  float* pf = aout + (long)blockIdx.x * 2048;
  u16x4 h0 = ((const u16x4*)ph)[tid];
  u16x4 h1 = ((const u16x4*)ph)[tid + 256];
  f4 v0, v1;
#pragma unroll
  for (int j = 0; j < 4; ++j) { v0[j] = h2f(h0[j]); v1[j] = h2f(h1[j]); }
  float m = fmaxf(fmaxf(fmaxf(v0[0], v0[1]), fmaxf(v0[2], v0[3])),
                  fmaxf(fmaxf(v1[0], v1[1]), fmaxf(v1[2], v1[3])));
#pragma unroll
  for (int o = 32; o >= 1; o >>= 1) m = fmaxf(m, __shfl_xor(m, o));
  __shared__ float redm[4], reds[4];
  if ((tid & 63) == 0) redm[tid >> 6] = m;
  __syncthreads();
  m = fmaxf(fmaxf(redm[0], redm[1]), fmaxf(redm[2], redm[3]));
  float s = 0.f;
#pragma unroll
  for (int j = 0; j < 4; ++j) { v0[j] = __expf(v0[j] - m); s += v0[j]; }
#pragma unroll
  for (int j = 0; j < 4; ++j) { v1[j] = __expf(v1[j] - m); s += v1[j]; }
#pragma unroll
  for (int o = 32; o >= 1; o >>= 1) s += __shfl_xor(s, o);
  if ((tid & 63) == 0) reds[tid >> 6] = s;
  __syncthreads();
  const float inv = 1.0f / (reds[0] + reds[1] + reds[2] + reds[3]);
  v0 *= inv; v1 *= inv;
  ((f4*)pf)[tid] = v0;
  ((f4*)pf)[tid + 256] = v1;
#pragma unroll
  for (int j = 0; j < 4; ++j) { h0[j] = f2h(v0[j]); h1[j] = f2h(v1[j]); }
  ((u16x4*)ph)[tid] = h0;
  ((u16x4*)ph)[tid + 256] = h1;
}

extern "C" void kernel_launch(void* const* d_in, const int* in_sizes, int n_in,
                              void* d_out, int out_size, void* d_ws, size_t ws_size,
                              hipStream_t stream) {
  const float* base  = (const float*)d_in[0];
  const float* x     = (const float*)d_in[1];
  const float* enc_t = (const float*)d_in[2];
  const float* enc_c = (const float*)d_in[3];
  const float* W     = (const float*)d_in[4];
  const float* bias  = (const float*)d_in[5];

  float* ctx  = (float*)d_out;                       // [B,C,T]
  float* attn = ctx + (long)B_ * C_ * T_;            // [B,T,S]

  const long NBTC = (long)B_ * T_ * C_;              // 8388608
  u16* ws   = (u16*)d_ws;
  u16* x_h  = ws;                   // fp16 [B,T,C]          [0, N)
  u16* et_h = ws + NBTC;            // fp16 [B,S,C]          [N, 2N)
  u16* pre  = ws + 2 * NBTC;        // fp16 pre_a->attn_h    [2N, 6N)  (= B*T*S)
  u16* ec_h = ws + 6 * NBTC;        // fp16 [B,C,S]          [6N, 7N)
  u16* w_h  = ws + 7 * NBTC;        // fp16 [C,C]
  u16* w_l  = w_h + (long)C_ * C_;  // fp16 [C,C] (exact residual)
  // total: (7*NBTC + 2*C*C)*2 B = 118,489,088 B — identical to proven round-0 footprint

  // target fp16 hi/lo in d_out ctx region (2*NBTC u16 = exactly 32 MB, dead until GEMM3)
  u16* t_h = (u16*)d_out;
  u16* t_l = t_h + NBTC;

  dim3 tb(32, 8);
  // x [B,C,T] -> x_h fp16 [B,T,C]
  transpose_kernel<<<dim3(T_ / 32, C_ / 32, B_), tb, 0, stream>>>(x, x_h, T_);
  // enc_t [B,C,S] -> et_h fp16 [B,S,C]
  transpose_kernel<<<dim3(S_ / 32, C_ / 32, B_), tb, 0, stream>>>(enc_t, et_h, S_);
  // enc_c -> ec_h fp16 (no transpose)
  split_kernel<0><<<2048, 256, 0, stream>>>(enc_c, ec_h, nullptr, (long)B_ * C_ * S_ / 4);
  // W -> w_h + w_l (exact fp16 split)
  split_kernel<1><<<256, 256, 0, stream>>>(W, w_h, w_l, (long)C_ * C_ / 4);

  // GEMM1 (fp16 2-pass, W split exact): target + epilogue -> t_h/t_l
  gemm1_kernel<<<dim3(C_ / 128, T_ / 128, B_), 256, 0, stream>>>(
      x_h, w_h, w_l, base, bias, t_h, t_l);

  // GEMM2 (256x256 8-phase fp16, 16 k-tiles: Th.E + Tl.E) -> pre_a fp16 (ws)
  gemm8p_kernel<16, 8, 512, 4, 1><<<dim3(S_ / 256, T_ / 256, B_), 512, 0, stream>>>(
      t_h, t_l, et_h, pre,
      (long)T_ * C_, (long)S_ * C_, (long)T_ * S_, S_);

  // softmax: fp16 pre_a -> f32 attn (d_out) + fp16 attn in place
  softmax_kernel<<<B_ * T_, 256, 0, stream>>>(pre, attn);

  // GEMM3 (128x256 8-phase fp16, MF=2, 32 k-tiles, full occupancy):
  // ctx[c][t] = sum_s ec[c][s] * attn_h[t][s]
  gemm8p_kernel<32, 32, 2048, 2, 0><<<dim3(T_ / 256, C_ / 128, B_), 512, 0, stream>>>(
      ec_h, ec_h, pre, ctx,
      (long)C_ * S_, (long)T_ * S_, (long)C_ * T_, T_);

  (void)in_sizes; (void)n_in; (void)out_size; (void)ws_size;
}

// Round 11
// 241.530 us; speedup vs baseline: 1.3553x; 1.0111x over previous
//
#include <hip/hip_runtime.h>

typedef unsigned short u16;
typedef __attribute__((ext_vector_type(4))) float f4;
typedef __attribute__((ext_vector_type(8))) short bf8;
typedef __attribute__((ext_vector_type(8))) _Float16 h8;
typedef __attribute__((ext_vector_type(4))) unsigned short u16x4;

#define B_ 8
#define C_ 512
#define T_ 2048
#define S_ 2048
#define SCALE_W 0.70710678118654752440f

__device__ __forceinline__ u16 f2h(float f) {
  return __builtin_bit_cast(u16, (_Float16)f);
}
__device__ __forceinline__ float h2f(u16 h) {
  return (float)__builtin_bit_cast(_Float16, h);
}

__device__ __forceinline__ void gload16(const u16* g, u16* l) {
  __builtin_amdgcn_global_load_lds((__attribute__((address_space(1))) const void*)g,
                                   (__attribute__((address_space(3))) void*)l, 16, 0, 0);
}

#define MEMF() asm volatile("" ::: "memory")
#define BAR()  do { MEMF(); __builtin_amdgcn_s_barrier(); MEMF(); } while (0)
#define LGKM0() do { asm volatile("s_waitcnt lgkmcnt(0)" ::: "memory"); \
                     __builtin_amdgcn_sched_barrier(0); } while (0)

// ---------- prep: fused transpose x AND enc_t [B,C,2048] -> [B,2048,C] fp16.
// z<8 -> x, z>=8 -> enc_t. Writes vectorized u16x4 (8B/lane, 64B segments per 8 lanes).
__global__ __launch_bounds__(256) void transpose2_kernel(
    const float* __restrict__ inx, const float* __restrict__ inet,
    u16* __restrict__ ox, u16* __restrict__ oet)
{
  __shared__ float t[32][33];
  const int tid = threadIdx.x;
  const int tx = tid & 31, ty = tid >> 5;
  int z = blockIdx.z;
  const float* in = (z < 8) ? inx : inet;
  u16* oh = (z < 8) ? ox : oet;
  z &= 7;
  const long cbase = (long)z * C_ + blockIdx.y * 32;
  const long xbase = (long)blockIdx.x * 32;
  const float* ip = in + cbase * 2048 + xbase;
#pragma unroll
  for (int i = 0; i < 4; ++i)
    t[ty + i * 8][tx] = ip[(long)(ty + i * 8) * 2048 + tx];
  __syncthreads();
  // write: row xx = tid>>3 (0..31), cols c4 = (tid&7)*4 .. +3 (one u16x4)
  const int xx = tid >> 3;
  const int c4 = (tid & 7) * 4;
  u16x4 v;
#pragma unroll
  for (int k = 0; k < 4; ++k) v[k] = f2h(t[c4 + k][xx]);
  *(u16x4*)&oh[((long)z * 2048 + xbase + xx) * C_ + blockIdx.y * 32 + c4] = v;
}

// ---------- prep: elementwise f32 -> fp16. LO=1: exact hi/lo split pair.
template<int LO>
__global__ __launch_bounds__(256) void split_kernel(
    const float* __restrict__ in, u16* __restrict__ oh, u16* __restrict__ ol, long n4)
{
  long i = (long)blockIdx.x * 256 + threadIdx.x;
  const long stride = (long)gridDim.x * 256;
  for (; i < n4; i += stride) {
    f4 v = ((const f4*)in)[i];
    u16x4 hv, lv;
#pragma unroll
    for (int j = 0; j < 4; ++j) {
      u16 h = f2h(v[j]);
      hv[j] = h;
      if (LO) lv[j] = f2h(v[j] - h2f(h));
    }
    ((u16x4*)oh)[i] = hv;
    if (LO) ((u16x4*)ol)[i] = lv;
  }
}

// ---------- GEMM1 (128x128, BK=32, fp16 2-pass, W exact-split):
// t[t][o] = (sum_c x[t][c]*(Wh+Wl)[o][c] + base[o][t] + bias[o]) * SCALE, fp16 hi/lo store
__global__ __launch_bounds__(256, 2) void gemm1_kernel(
    const u16* __restrict__ A,
    const u16* __restrict__ Bh, const u16* __restrict__ Bl,
    const float* __restrict__ baseO, const float* __restrict__ bias,
    u16* __restrict__ outH, u16* __restrict__ outL)
{
  constexpr int BM = 128, BK = 32, K = C_, N = C_;
  constexpr int TILE = BM * BK;
  __shared__ u16 lA[TILE], lBh[TILE], lBl[TILE];

  const int tid = threadIdx.x;
  const int wid = tid >> 6;
  const int lane = tid & 63;
  const int wr = wid >> 1, wc = wid & 1;
  const int bz = blockIdx.z;
  const int m0 = blockIdx.y * BM;
  const int n0 = blockIdx.x * BM;

  const u16* gA  = A + ((long)bz * T_ + m0) * K;
  const u16* gBh = Bh + (long)n0 * K;
  const u16* gBl = Bl + (long)n0 * K;

  const int srow = tid >> 2;
  const int skoff = (tid & 3) * 8;
  const int ldsOff = wid * 512;

  f4 acc[4][4] = {};

  for (int k0 = 0; k0 < K; k0 += BK) {
    __syncthreads();
#pragma unroll
    for (int c = 0; c < 2; ++c) {
      const long go = (long)(c * 64 + srow) * K + k0 + skoff;
      const int lo = c * 2048 + ldsOff;
      gload16(gA + go, lA + lo);
      gload16(gBh + go, lBh + lo);
      gload16(gBl + go, lBl + lo);
    }
    asm volatile("s_waitcnt vmcnt(0)" ::: "memory");
    __syncthreads();

    bf8 a_[4], b_h[4], b_l[4];
    const int fr = lane & 15;
    const int fk = (lane >> 4) * 8;
#pragma unroll
    for (int i = 0; i < 4; ++i) {
      a_[i]  = *(const bf8*)&lA[(wr * 64 + i * 16 + fr) * BK + fk];
      b_h[i] = *(const bf8*)&lBh[(wc * 64 + i * 16 + fr) * BK + fk];
      b_l[i] = *(const bf8*)&lBl[(wc * 64 + i * 16 + fr) * BK + fk];
    }
#pragma unroll
    for (int mi = 0; mi < 4; ++mi)
#pragma unroll
      for (int ni = 0; ni < 4; ++ni) {
        acc[mi][ni] = __builtin_amdgcn_mfma_f32_16x16x32_f16(
            __builtin_bit_cast(h8, a_[mi]), __builtin_bit_cast(h8, b_h[ni]),
            acc[mi][ni], 0, 0, 0);
        acc[mi][ni] = __builtin_amdgcn_mfma_f32_16x16x32_f16(
            __builtin_bit_cast(h8, a_[mi]), __builtin_bit_cast(h8, b_l[ni]),
            acc[mi][ni], 0, 0, 0);
      }
  }

  const int fr = lane & 15;
  const int r4 = (lane >> 4) * 4;
#pragma unroll
  for (int mi = 0; mi < 4; ++mi) {
#pragma unroll
    for (int ni = 0; ni < 4; ++ni) {
      const int gn = n0 + wc * 64 + ni * 16 + fr;
      const long gmb = m0 + wr * 64 + mi * 16 + r4;
      // base in original [B][C][T] layout: channel gn, t = gmb..gmb+3 (f4 aligned)
      f4 bv = *(const f4*)(baseO + ((long)bz * C_ + gn) * T_ + gmb);
      const float bs = bias[gn];
#pragma unroll
      for (int r = 0; r < 4; ++r) {
        float val = (acc[mi][ni][r] + bv[r] + bs) * SCALE_W;
        const long idx = ((long)bz * T_ + gmb + r) * (long)N + gn;
        u16 h = f2h(val);
        outH[idx] = h;
        outL[idx] = f2h(val - h2f(h));
      }
    }
  }
}

// ---------- 256-col / BK=64 / 8-wave phase-pipelined fp16 GEMM (counted vmcnt)
// MF=4 -> BM=256 (proven round-7/8 kernel), MF=2 -> BM=128 (full occupancy, round-10).
// LDS slot swizzle (proven conflict-free, round 7): store LDS[R][slot ^ (R&7)].
template<int MF, int LDK>
__device__ __forceinline__ void stage_a(const u16* g, u16* l) {
  gload16(g, l);
  if (MF == 4) gload16(g + 64 * LDK, l + 4096);  // +64 rows: same &7 -> same swizzle
}
template<int LDK>
__device__ __forceinline__ void stage_b(const u16* g, u16* l) {
  gload16(g, l);
  gload16(g + 64 * LDK, l + 4096);
}
template<int NF>
__device__ __forceinline__ void rd_frags(bf8 (&d)[NF][2], const u16* p, int k0o, int k1o) {
#pragma unroll
  for (int i = 0; i < NF; ++i) {
    d[i][0] = *(const bf8*)&p[i * 1024 + k0o];
    d[i][1] = *(const bf8*)&p[i * 1024 + k1o];
  }
}
template<int MH, int NH, int MF>
__device__ __forceinline__ void mmq(f4 (&acc)[2 * MF][4], const bf8 (&a)[MF][2],
                                    const bf8 (&b)[2][2]) {
  __builtin_amdgcn_s_setprio(1);
#pragma unroll
  for (int mi = 0; mi < MF; ++mi)
#pragma unroll
    for (int ni = 0; ni < 2; ++ni)
#pragma unroll
      for (int ks = 0; ks < 2; ++ks)
        acc[MH * MF + mi][NH * 2 + ni] = __builtin_amdgcn_mfma_f32_16x16x32_f16(
            __builtin_bit_cast(h8, a[mi][ks]), __builtin_bit_cast(h8, b[ni][ks]),
            acc[MH * MF + mi][NH * 2 + ni], 0, 0, 0);
  __builtin_amdgcn_s_setprio(0);
}

template<int NT, int TPP, int LDK, int MF, int OUT16>
__global__ __launch_bounds__(512, 2) void gemm8p_kernel(
    const u16* __restrict__ A0, const u16* __restrict__ A1,
    const u16* __restrict__ B0,
    void* __restrict__ outP,
    long sA, long sB, long sO, int Nr)
{
  // A: [2buf][BM][64] @0 (BM = MF*64); B: [2buf][256][64] @ MF*8192 (u16 units)
  __shared__ u16 lds[MF * 8192 + 32768];
  const int tid = threadIdx.x;
  const int wid = tid >> 6, lane = tid & 63;
  const int wr = wid >> 2, wc = wid & 3;

  // bijective XCD swizzle (nwg divisible by 8 for all our launches)
  const int gx = gridDim.x, gy = gridDim.y;
  int lin = blockIdx.x + gx * (blockIdx.y + gy * blockIdx.z);
  const int nwg = gx * gy * (int)gridDim.z;
  lin = (lin & 7) * (nwg >> 3) + (lin >> 3);
  const int bx = lin % gx;
  const int tmp = lin / gx;
  const int by = tmp % gy, bz = tmp / gy;

  const int m0 = by * (MF * 64), n0 = bx * 256;
  const u16* gA0 = A0 + (long)bz * sA + (long)m0 * LDK;
  const u16* gA1 = A1 + (long)bz * sA + (long)m0 * LDK;
  const u16* gB  = B0 + (long)bz * sB + (long)n0 * LDK;

  // staging: LDS dest linear (slot = tid&7); source slot = (tid&7) ^ (srow&7)
  const int srow = tid >> 3;                                   // 0..63
  const int scol = (((tid & 7) ^ (srow & 7)) * 8);             // u16
  const int dstA = tid * 8;                                    // u16

  // fragment-read: nominal slot = ks*4 + g; swizzled col = ((ks*4+g) ^ (lane&7))*8
  const int fr = lane & 15;
  const int k0o = (((lane >> 4) ^ (lane & 7)) * 8);            // ks=0
  const int k1o = k0o ^ 32;                                    // ks=1 (slot bit 2)
  const int abase = (wr * (MF * 32) + fr) * 64;
  const int bbase = MF * 8192 + (wc * 64 + fr) * 64;

  f4 acc[2 * MF][4] = {};

#define SRC_A(tt) ((((tt) / TPP) == 0 ? gA0 : gA1) + ((tt) % TPP) * 64)
#define SRC_B(tt) (gB + ((tt) % TPP) * 64)
#define STAGE_A(tt, h) stage_a<MF, LDK>( \
    SRC_A(tt) + (long)((h) * (MF * 32) + srow) * LDK + scol, \
    lds + (((tt) & 1) * (MF * 4096) + (h) * (MF * 2048) + dstA))
#define STAGE_B(tt, h) stage_b<LDK>( \
    SRC_B(tt) + (long)((h) * 128 + srow) * LDK + scol, \
    lds + (MF * 8192 + ((tt) & 1) * 16384 + (h) * 8192 + dstA))

  // prologue: tile0 fully + B(1,0)
  STAGE_B(0, 0); STAGE_B(0, 1); STAGE_A(0, 0); STAGE_A(0, 1); STAGE_B(1, 0);
  asm volatile("s_waitcnt vmcnt(2)" ::: "memory");  // tile0 landed; B(1)h0 may fly
  BAR();

  bf8 af[MF][2], b0[2][2], b1[2][2];
  for (int kt = 0; kt < NT - 1; ++kt) {
    const int cur = kt & 1;
    const u16* la = lds + cur * (MF * 4096) + abase;
    const u16* lb = lds + cur * 16384 + bbase;
    // ---- ph1: Q(0,0)
    rd_frags(af, la, k0o, k1o);
    rd_frags(b0, lb, k0o, k1o);
    STAGE_B(kt + 1, 1);
    BAR(); LGKM0();
    mmq<0, 0, MF>(acc, af, b0);
    BAR();
    // ---- ph2: Q(0,1)
    rd_frags(b1, lb + 2048, k0o, k1o);
    STAGE_A(kt + 1, 0);
    BAR(); LGKM0();
    mmq<0, 1, MF>(acc, af, b1);
    BAR();
    // ---- ph3: Q(1,0)
    rd_frags(af, la + MF * 1024, k0o, k1o);
    STAGE_A(kt + 1, 1);
    BAR(); LGKM0();
    mmq<1, 0, MF>(acc, af, b0);
    BAR();
    // ---- ph4: Q(1,1)
    {
      int t2 = kt + 2; if (t2 > NT - 1) t2 = NT - 1;  // harmless duplicate re-stage at tail
      STAGE_B(t2, 0);
    }
    BAR();
    mmq<1, 1, MF>(acc, af, b1);
    if (kt == NT - 2) { asm volatile("s_waitcnt vmcnt(0)" ::: "memory"); }
    else             { asm volatile("s_waitcnt vmcnt(2)" ::: "memory"); }
    BAR();
  }
  // peeled final tile (no staging)
  {
    const int cur = (NT - 1) & 1;
    const u16* la = lds + cur * (MF * 4096) + abase;
    const u16* lb = lds + cur * 16384 + bbase;
    rd_frags(af, la, k0o, k1o);
    rd_frags(b0, lb, k0o, k1o);
    BAR(); LGKM0();
    mmq<0, 0, MF>(acc, af, b0);
    BAR();
    rd_frags(b1, lb + 2048, k0o, k1o);
    BAR(); LGKM0();
    mmq<0, 1, MF>(acc, af, b1);
    BAR();
    rd_frags(af, la + MF * 1024, k0o, k1o);
    BAR(); LGKM0();
    mmq<1, 0, MF>(acc, af, b0);
    BAR();
    mmq<1, 1, MF>(acc, af, b1);
  }
#undef SRC_A
#undef SRC_B
#undef STAGE_A
#undef STAGE_B

  // epilogue: C-write (f32 or fp16)
  const int r4 = (lane >> 4) * 4;
#pragma unroll
  for (int am = 0; am < 2 * MF; ++am) {
#pragma unroll
    for (int an = 0; an < 4; ++an) {
      const long gm = m0 + wr * (MF * 32) + am * 16 + r4;
      const int gn = n0 + wc * 64 + an * 16 + fr;
      if (OUT16) {
        u16* po = (u16*)outP + (long)bz * sO + gm * (long)Nr + gn;
#pragma unroll
        for (int r = 0; r < 4; ++r) po[(long)r * Nr] = f2h(acc[am][an][r]);
      } else {
        float* po = (float*)outP + (long)bz * sO + gm * (long)Nr + gn;
#pragma unroll
        for (int r = 0; r < 4; ++r) po[(long)r * Nr] = acc[am][an][r];
      }
    }
  }
}

// ---------- softmax: read fp16 pre_a row, write f32 attn (d_out) + fp16 back in place
__global__ __launch_bounds__(256) void softmax_kernel(u16* __restrict__ pah,
                                                      float* __restrict__ aout) {
  const int tid = threadIdx.x;
  u16* ph = pah + (long)blockIdx.x * 2048;
  float* pf = aout + (long)blockIdx.x * 2048;
  u16x4 h0 = ((const u16x4*)ph)[tid];
  u16x4 h1 = ((const u16x4*)ph)[tid + 256];
  f4 v0, v1;
#pragma unroll
  for (int j = 0; j < 4; ++j) { v0[j] = h2f(h0[j]); v1[j] = h2f(h1[j]); }
  float m = fmaxf(fmaxf(fmaxf(v0[0], v0[1]), fmaxf(v0[2], v0[3])),
                  fmaxf(fmaxf(v1[0], v1[1]), fmaxf(v1[2], v1[3])));
#pragma unroll
  for (int o = 32; o >= 1; o >>= 1) m = fmaxf(m, __shfl_xor(m, o));
  __shared__ float redm[4], reds[4];
  if ((tid & 63) == 0) redm[tid >> 6] = m;
  __syncthreads();
  m = fmaxf(fmaxf(redm[0], redm[1]), fmaxf(redm[2], redm[3]));
  float s = 0.f;
#pragma unroll
  for (int j = 0; j < 4; ++j) { v0[j] = __expf(v0[j] - m); s += v0[j]; }
#pragma unroll
  for (int j = 0; j < 4; ++j) { v1[j] = __expf(v1[j] - m); s += v1[j]; }
#pragma unroll
  for (int o = 32; o >= 1; o >>= 1) s += __shfl_xor(s, o);
  if ((tid & 63) == 0) reds[tid >> 6] = s;
  __syncthreads();
  const float inv = 1.0f / (reds[0] + reds[1] + reds[2] + reds[3]);
  v0 *= inv; v1 *= inv;
  ((f4*)pf)[tid] = v0;
  ((f4*)pf)[tid + 256] = v1;
#pragma unroll
  for (int j = 0; j < 4; ++j) { h0[j] = f2h(v0[j]); h1[j] = f2h(v1[j]); }
  ((u16x4*)ph)[tid] = h0;
  ((u16x4*)ph)[tid + 256] = h1;
}

extern "C" void kernel_launch(void* const* d_in, const int* in_sizes, int n_in,
                              void* d_out, int out_size, void* d_ws, size_t ws_size,
                              hipStream_t stream) {
  const float* base  = (const float*)d_in[0];
  const float* x     = (const float*)d_in[1];
  const float* enc_t = (const float*)d_in[2];
  const float* enc_c = (const float*)d_in[3];
  const float* W     = (const float*)d_in[4];
  const float* bias  = (const float*)d_in[5];

  float* ctx  = (float*)d_out;                       // [B,C,T]
  float* attn = ctx + (long)B_ * C_ * T_;            // [B,T,S]

  const long NBTC = (long)B_ * T_ * C_;              // 8388608
  u16* ws   = (u16*)d_ws;
  u16* x_h  = ws;                   // fp16 [B,T,C]          [0, N)
  u16* et_h = ws + NBTC;            // fp16 [B,S,C]          [N, 2N)
  u16* pre  = ws + 2 * NBTC;        // fp16 pre_a->attn_h    [2N, 6N)  (= B*T*S)
  u16* ec_h = ws + 6 * NBTC;        // fp16 [B,C,S]          [6N, 7N)
  u16* w_h  = ws + 7 * NBTC;        // fp16 [C,C]
  u16* w_l  = w_h + (long)C_ * C_;  // fp16 [C,C] (exact residual)
  // total: (7*NBTC + 2*C*C)*2 B = 118,489,088 B — proven footprint

  // target fp16 hi/lo in d_out ctx region (2*NBTC u16 = exactly 32 MB, dead until GEMM3)
  u16* t_h = (u16*)d_out;
  u16* t_l = t_h + NBTC;

  // fused transpose: x -> x_h, enc_t -> et_h (both [B,2048,C] fp16, u16x4 writes)
  transpose2_kernel<<<dim3(2048 / 32, C_ / 32, 2 * B_), 256, 0, stream>>>(
      x, enc_t, x_h, et_h);
  // enc_c -> ec_h fp16 (no transpose)
  split_kernel<0><<<2048, 256, 0, stream>>>(enc_c, ec_h, nullptr, (long)B_ * C_ * S_ / 4);
  // W -> w_h + w_l (exact fp16 split)
  split_kernel<1><<<256, 256, 0, stream>>>(W, w_h, w_l, (long)C_ * C_ / 4);

  // GEMM1 (fp16 2-pass, W split exact): target + epilogue -> t_h/t_l
  gemm1_kernel<<<dim3(C_ / 128, T_ / 128, B_), 256, 0, stream>>>(
      x_h, w_h, w_l, base, bias, t_h, t_l);

  // GEMM2 (256x256 8-phase fp16, 16 k-tiles: Th.E + Tl.E) -> pre_a fp16 (ws)
  gemm8p_kernel<16, 8, 512, 4, 1><<<dim3(S_ / 256, T_ / 256, B_), 512, 0, stream>>>(
      t_h, t_l, et_h, pre,
      (long)T_ * C_, (long)S_ * C_, (long)T_ * S_, S_);

  // softmax: fp16 pre_a -> f32 attn (d_out) + fp16 attn in place
  softmax_kernel<<<B_ * T_, 256, 0, stream>>>(pre, attn);

  // GEMM3 (128x256 8-phase fp16, MF=2, 32 k-tiles, full occupancy):
  // ctx[c][t] = sum_s ec[c][s] * attn_h[t][s]
  gemm8p_kernel<32, 32, 2048, 2, 0><<<dim3(T_ / 256, C_ / 128, B_), 512, 0, stream>>>(
      ec_h, ec_h, pre, ctx,
      (long)C_ * S_, (long)T_ * S_, (long)C_ * T_, T_);

  (void)in_sizes; (void)n_in; (void)out_size; (void)ws_size;
}

// Round 12
// 235.025 us; speedup vs baseline: 1.3928x; 1.0277x over previous
//
#include <hip/hip_runtime.h>

typedef unsigned short u16;
typedef __attribute__((ext_vector_type(4))) float f4;
typedef __attribute__((ext_vector_type(8))) short bf8;
typedef __attribute__((ext_vector_type(8))) _Float16 h8;
typedef __attribute__((ext_vector_type(4))) unsigned short u16x4;

#define B_ 8
#define C_ 512
#define T_ 2048
#define S_ 2048
#define SCALE_W 0.70710678118654752440f

__device__ __forceinline__ u16 f2h(float f) {
  return __builtin_bit_cast(u16, (_Float16)f);
}
__device__ __forceinline__ float h2f(u16 h) {
  return (float)__builtin_bit_cast(_Float16, h);
}

__device__ __forceinline__ void gload16(const u16* g, u16* l) {
  __builtin_amdgcn_global_load_lds((__attribute__((address_space(1))) const void*)g,
                                   (__attribute__((address_space(3))) void*)l, 16, 0, 0);
}

#define MEMF() asm volatile("" ::: "memory")
#define BAR()  do { MEMF(); __builtin_amdgcn_s_barrier(); MEMF(); } while (0)
#define LGKM0() do { asm volatile("s_waitcnt lgkmcnt(0)" ::: "memory"); \
                     __builtin_amdgcn_sched_barrier(0); } while (0)

// ---------- merged prep: one launch, grid dim3(64, 16, 25).
// z<8:  transpose x   [B,C,T]->[B,T,C] fp16 (u16x4 vectorized writes)
// z<16: transpose et  [B,C,S]->[B,S,C] fp16
// z<24: enc_c convert f32->fp16 (batch z-16; 1024 blocks x 256 thr x 1 f4 = exact)
// z=24: W exact fp16 hi/lo split (65536 f4 over first 65536 threads)
__global__ __launch_bounds__(256) void prep_kernel(
    const float* __restrict__ x, const float* __restrict__ et,
    const float* __restrict__ ec, const float* __restrict__ W,
    u16* __restrict__ ox, u16* __restrict__ oet,
    u16* __restrict__ oec, u16* __restrict__ owh, u16* __restrict__ owl)
{
  const int z = blockIdx.z;
  const int tid = threadIdx.x;
  if (z < 16) {
    __shared__ float t[32][33];
    const int tx = tid & 31, ty = tid >> 5;
    const float* in = (z < 8) ? x : et;
    u16* oh = (z < 8) ? ox : oet;
    const int b = z & 7;
    const long cbase = (long)b * C_ + blockIdx.y * 32;
    const long xbase = (long)blockIdx.x * 32;
    const float* ip = in + cbase * 2048 + xbase;
#pragma unroll
    for (int i = 0; i < 4; ++i)
      t[ty + i * 8][tx] = ip[(long)(ty + i * 8) * 2048 + tx];
    __syncthreads();
    const int xx = tid >> 3;
    const int c4 = (tid & 7) * 4;
    u16x4 v;
#pragma unroll
    for (int k = 0; k < 4; ++k) v[k] = f2h(t[c4 + k][xx]);
    *(u16x4*)&oh[((long)b * 2048 + xbase + xx) * C_ + blockIdx.y * 32 + c4] = v;
  } else if (z < 24) {
    const int b = z - 16;
    const long i = (long)b * ((long)C_ * S_ / 4) +
                   (long)(blockIdx.y * 64 + blockIdx.x) * 256 + tid;
    f4 v = ((const f4*)ec)[i];
    u16x4 hv;
#pragma unroll
    for (int j = 0; j < 4; ++j) hv[j] = f2h(v[j]);
    ((u16x4*)oec)[i] = hv;
  } else {
    const long i = (long)(blockIdx.y * 64 + blockIdx.x) * 256 + tid;
    if (i < (long)C_ * C_ / 4) {
      f4 v = ((const f4*)W)[i];
      u16x4 hv, lv;
#pragma unroll
      for (int j = 0; j < 4; ++j) {
        u16 h = f2h(v[j]);
        hv[j] = h;
        lv[j] = f2h(v[j] - h2f(h));
      }
      ((u16x4*)owh)[i] = hv;
      ((u16x4*)owl)[i] = lv;
    }
  }
}

// ---------- GEMM1 (128x128, BK=32, fp16 2-pass, W exact-split):
// t[t][o] = (sum_c x[t][c]*(Wh+Wl)[o][c] + base[o][t] + bias[o]) * SCALE, fp16 hi/lo store
__global__ __launch_bounds__(256, 2) void gemm1_kernel(
    const u16* __restrict__ A,
    const u16* __restrict__ Bh, const u16* __restrict__ Bl,
    const float* __restrict__ baseO, const float* __restrict__ bias,
    u16* __restrict__ outH, u16* __restrict__ outL)
{
  constexpr int BM = 128, BK = 32, K = C_, N = C_;
  constexpr int TILE = BM * BK;
  __shared__ u16 lA[TILE], lBh[TILE], lBl[TILE];

  const int tid = threadIdx.x;
  const int wid = tid >> 6;
  const int lane = tid & 63;
  const int wr = wid >> 1, wc = wid & 1;
  const int bz = blockIdx.z;
  const int m0 = blockIdx.y * BM;
  const int n0 = blockIdx.x * BM;

  const u16* gA  = A + ((long)bz * T_ + m0) * K;
  const u16* gBh = Bh + (long)n0 * K;
  const u16* gBl = Bl + (long)n0 * K;

  const int srow = tid >> 2;
  const int skoff = (tid & 3) * 8;
  const int ldsOff = wid * 512;

  f4 acc[4][4] = {};

  for (int k0 = 0; k0 < K; k0 += BK) {
    __syncthreads();
#pragma unroll
    for (int c = 0; c < 2; ++c) {
      const long go = (long)(c * 64 + srow) * K + k0 + skoff;
      const int lo = c * 2048 + ldsOff;
      gload16(gA + go, lA + lo);
      gload16(gBh + go, lBh + lo);
      gload16(gBl + go, lBl + lo);
    }
    asm volatile("s_waitcnt vmcnt(0)" ::: "memory");
    __syncthreads();

    bf8 a_[4], b_h[4], b_l[4];
    const int fr = lane & 15;
    const int fk = (lane >> 4) * 8;
#pragma unroll
    for (int i = 0; i < 4; ++i) {
      a_[i]  = *(const bf8*)&lA[(wr * 64 + i * 16 + fr) * BK + fk];
      b_h[i] = *(const bf8*)&lBh[(wc * 64 + i * 16 + fr) * BK + fk];
      b_l[i] = *(const bf8*)&lBl[(wc * 64 + i * 16 + fr) * BK + fk];
    }
#pragma unroll
    for (int mi = 0; mi < 4; ++mi)
#pragma unroll
      for (int ni = 0; ni < 4; ++ni) {
        acc[mi][ni] = __builtin_amdgcn_mfma_f32_16x16x32_f16(
            __builtin_bit_cast(h8, a_[mi]), __builtin_bit_cast(h8, b_h[ni]),
            acc[mi][ni], 0, 0, 0);
        acc[mi][ni] = __builtin_amdgcn_mfma_f32_16x16x32_f16(
            __builtin_bit_cast(h8, a_[mi]), __builtin_bit_cast(h8, b_l[ni]),
            acc[mi][ni], 0, 0, 0);
      }
  }

  const int fr = lane & 15;
  const int r4 = (lane >> 4) * 4;
#pragma unroll
  for (int mi = 0; mi < 4; ++mi) {
#pragma unroll
    for (int ni = 0; ni < 4; ++ni) {
      const int gn = n0 + wc * 64 + ni * 16 + fr;
      const long gmb = m0 + wr * 64 + mi * 16 + r4;
      // base in original [B][C][T] layout: channel gn, t = gmb..gmb+3 (f4 aligned)
      f4 bv = *(const f4*)(baseO + ((long)bz * C_ + gn) * T_ + gmb);
      const float bs = bias[gn];
#pragma unroll
      for (int r = 0; r < 4; ++r) {
        float val = (acc[mi][ni][r] + bv[r] + bs) * SCALE_W;
        const long idx = ((long)bz * T_ + gmb + r) * (long)N + gn;
        u16 h = f2h(val);
        outH[idx] = h;
        outL[idx] = f2h(val - h2f(h));
      }
    }
  }
}

// ---------- 256-col / BK=64 / 8-wave phase-pipelined fp16 GEMM (counted vmcnt)
// MF=4 -> BM=256 (proven round-7/8 kernel), MF=2 -> BM=128 (full occupancy, round-10).
// LDS slot swizzle (proven conflict-free, round 7): store LDS[R][slot ^ (R&7)].
template<int MF, int LDK>
__device__ __forceinline__ void stage_a(const u16* g, u16* l) {
  gload16(g, l);
  if (MF == 4) gload16(g + 64 * LDK, l + 4096);  // +64 rows: same &7 -> same swizzle
}
template<int LDK>
__device__ __forceinline__ void stage_b(const u16* g, u16* l) {
  gload16(g, l);
  gload16(g + 64 * LDK, l + 4096);
}
template<int NF>
__device__ __forceinline__ void rd_frags(bf8 (&d)[NF][2], const u16* p, int k0o, int k1o) {
#pragma unroll
  for (int i = 0; i < NF; ++i) {
    d[i][0] = *(const bf8*)&p[i * 1024 + k0o];
    d[i][1] = *(const bf8*)&p[i * 1024 + k1o];
  }
}
template<int MH, int NH, int MF>
__device__ __forceinline__ void mmq(f4 (&acc)[2 * MF][4], const bf8 (&a)[MF][2],
                                    const bf8 (&b)[2][2]) {
  __builtin_amdgcn_s_setprio(1);
#pragma unroll
  for (int mi = 0; mi < MF; ++mi)
#pragma unroll
    for (int ni = 0; ni < 2; ++ni)
#pragma unroll
      for (int ks = 0; ks < 2; ++ks)
        acc[MH * MF + mi][NH * 2 + ni] = __builtin_amdgcn_mfma_f32_16x16x32_f16(
            __builtin_bit_cast(h8, a[mi][ks]), __builtin_bit_cast(h8, b[ni][ks]),
            acc[MH * MF + mi][NH * 2 + ni], 0, 0, 0);
  __builtin_amdgcn_s_setprio(0);
}

template<int NT, int TPP, int LDK, int MF, int OUT16>
__global__ __launch_bounds__(512, 2) void gemm8p_kernel(
    const u16* __restrict__ A0, const u16* __restrict__ A1,
    const u16* __restrict__ B0,
    void* __restrict__ outP,
    long sA, long sB, long sO, int Nr)
{
  // A: [2buf][BM][64] @0 (BM = MF*64); B: [2buf][256][64] @ MF*8192 (u16 units)
  __shared__ u16 lds[MF * 8192 + 32768];
  const int tid = threadIdx.x;
  const int wid = tid >> 6, lane = tid & 63;
  const int wr = wid >> 2, wc = wid & 3;

  // bijective XCD swizzle (nwg divisible by 8 for all our launches)
  const int gx = gridDim.x, gy = gridDim.y;
  int lin = blockIdx.x + gx * (blockIdx.y + gy * blockIdx.z);
  const int nwg = gx * gy * (int)gridDim.z;
  lin = (lin & 7) * (nwg >> 3) + (lin >> 3);
  const int bx = lin % gx;
  const int tmp = lin / gx;
  const int by = tmp % gy, bz = tmp / gy;

  const int m0 = by * (MF * 64), n0 = bx * 256;
  const u16* gA0 = A0 + (long)bz * sA + (long)m0 * LDK;
  const u16* gA1 = A1 + (long)bz * sA + (long)m0 * LDK;
  const u16* gB  = B0 + (long)bz * sB + (long)n0 * LDK;

  // staging: LDS dest linear (slot = tid&7); source slot = (tid&7) ^ (srow&7)
  const int srow = tid >> 3;                                   // 0..63
  const int scol = (((tid & 7) ^ (srow & 7)) * 8);             // u16
  const int dstA = tid * 8;                                    // u16

  // fragment-read: nominal slot = ks*4 + g; swizzled col = ((ks*4+g) ^ (lane&7))*8
  const int fr = lane & 15;
  const int k0o = (((lane >> 4) ^ (lane & 7)) * 8);            // ks=0
  const int k1o = k0o ^ 32;                                    // ks=1 (slot bit 2)
  const int abase = (wr * (MF * 32) + fr) * 64;
  const int bbase = MF * 8192 + (wc * 64 + fr) * 64;

  f4 acc[2 * MF][4] = {};

#define SRC_A(tt) ((((tt) / TPP) == 0 ? gA0 : gA1) + ((tt) % TPP) * 64)
#define SRC_B(tt) (gB + ((tt) % TPP) * 64)
#define STAGE_A(tt, h) stage_a<MF, LDK>( \
    SRC_A(tt) + (long)((h) * (MF * 32) + srow) * LDK + scol, \
    lds + (((tt) & 1) * (MF * 4096) + (h) * (MF * 2048) + dstA))
#define STAGE_B(tt, h) stage_b<LDK>( \
    SRC_B(tt) + (long)((h) * 128 + srow) * LDK + scol, \
    lds + (MF * 8192 + ((tt) & 1) * 16384 + (h) * 8192 + dstA))

  // prologue: tile0 fully + B(1,0)
  STAGE_B(0, 0); STAGE_B(0, 1); STAGE_A(0, 0); STAGE_A(0, 1); STAGE_B(1, 0);
  asm volatile("s_waitcnt vmcnt(2)" ::: "memory");  // tile0 landed; B(1)h0 may fly
  BAR();

  bf8 af[MF][2], b0[2][2], b1[2][2];
  for (int kt = 0; kt < NT - 1; ++kt) {
    const int cur = kt & 1;
    const u16* la = lds + cur * (MF * 4096) + abase;
    const u16* lb = lds + cur * 16384 + bbase;
    // ---- ph1: Q(0,0)
    rd_frags(af, la, k0o, k1o);
    rd_frags(b0, lb, k0o, k1o);
    STAGE_B(kt + 1, 1);
    BAR(); LGKM0();
    mmq<0, 0, MF>(acc, af, b0);
    BAR();
    // ---- ph2: Q(0,1)
    rd_frags(b1, lb + 2048, k0o, k1o);
    STAGE_A(kt + 1, 0);
    BAR(); LGKM0();
    mmq<0, 1, MF>(acc, af, b1);
    BAR();
    // ---- ph3: Q(1,0)
    rd_frags(af, la + MF * 1024, k0o, k1o);
    STAGE_A(kt + 1, 1);
    BAR(); LGKM0();
    mmq<1, 0, MF>(acc, af, b0);
    BAR();
    // ---- ph4: Q(1,1)
    {
      int t2 = kt + 2; if (t2 > NT - 1) t2 = NT - 1;  // harmless duplicate re-stage at tail
      STAGE_B(t2, 0);
    }
    BAR();
    mmq<1, 1, MF>(acc, af, b1);
    if (kt == NT - 2) { asm volatile("s_waitcnt vmcnt(0)" ::: "memory"); }
    else             { asm volatile("s_waitcnt vmcnt(2)" ::: "memory"); }
    BAR();
  }
  // peeled final tile (no staging)
  {
    const int cur = (NT - 1) & 1;
    const u16* la = lds + cur * (MF * 4096) + abase;
    const u16* lb = lds + cur * 16384 + bbase;
    rd_frags(af, la, k0o, k1o);
    rd_frags(b0, lb, k0o, k1o);
    BAR(); LGKM0();
    mmq<0, 0, MF>(acc, af, b0);
    BAR();
    rd_frags(b1, lb + 2048, k0o, k1o);
    BAR(); LGKM0();
    mmq<0, 1, MF>(acc, af, b1);
    BAR();
    rd_frags(af, la + MF * 1024, k0o, k1o);
    BAR(); LGKM0();
    mmq<1, 0, MF>(acc, af, b0);
    BAR();
    mmq<1, 1, MF>(acc, af, b1);
  }
#undef SRC_A
#undef SRC_B
#undef STAGE_A
#undef STAGE_B

  // epilogue: C-write (f32 or fp16)
  const int r4 = (lane >> 4) * 4;
#pragma unroll
  for (int am = 0; am < 2 * MF; ++am) {
#pragma unroll
    for (int an = 0; an < 4; ++an) {
      const long gm = m0 + wr * (MF * 32) + am * 16 + r4;
      const int gn = n0 + wc * 64 + an * 16 + fr;
      if (OUT16) {
        u16* po = (u16*)outP + (long)bz * sO + gm * (long)Nr + gn;
#pragma unroll
        for (int r = 0; r < 4; ++r) po[(long)r * Nr] = f2h(acc[am][an][r]);
      } else {
        float* po = (float*)outP + (long)bz * sO + gm * (long)Nr + gn;
#pragma unroll
        for (int r = 0; r < 4; ++r) po[(long)r * Nr] = acc[am][an][r];
      }
    }
  }
}

// ---------- softmax: read fp16 pre_a row, write f32 attn (d_out) + fp16 back in place
__global__ __launch_bounds__(256) void softmax_kernel(u16* __restrict__ pah,
                                                      float* __restrict__ aout) {
  const int tid = threadIdx.x;
  u16* ph = pah + (long)blockIdx.x * 2048;
  float* pf = aout + (long)blockIdx.x * 2048;
  u16x4 h0 = ((const u16x4*)ph)[tid];
  u16x4 h1 = ((const u16x4*)ph)[tid + 256];
  f4 v0, v1;
#pragma unroll
  for (int j = 0; j < 4; ++j) { v0[j] = h2f(h0[j]); v1[j] = h2f(h1[j]); }
  float m = fmaxf(fmaxf(fmaxf(v0[0], v0[1]), fmaxf(v0[2], v0[3])),
                  fmaxf(fmaxf(v1[0], v1[1]), fmaxf(v1[2], v1[3])));
#pragma unroll
  for (int o = 32; o >= 1; o >>= 1) m = fmaxf(m, __shfl_xor(m, o));
  __shared__ float redm[4], reds[4];
  if ((tid & 63) == 0) redm[tid >> 6] = m;
  __syncthreads();
  m = fmaxf(fmaxf(redm[0], redm[1]), fmaxf(redm[2], redm[3]));
  float s = 0.f;
#pragma unroll
  for (int j = 0; j < 4; ++j) { v0[j] = __expf(v0[j] - m); s += v0[j]; }
#pragma unroll
  for (int j = 0; j < 4; ++j) { v1[j] = __expf(v1[j] - m); s += v1[j]; }
#pragma unroll
  for (int o = 32; o >= 1; o >>= 1) s += __shfl_xor(s, o);
  if ((tid & 63) == 0) reds[tid >> 6] = s;
  __syncthreads();
  const float inv = 1.0f / (reds[0] + reds[1] + reds[2] + reds[3]);
  v0 *= inv; v1 *= inv;
  ((f4*)pf)[tid] = v0;
  ((f4*)pf)[tid + 256] = v1;
#pragma unroll
  for (int j = 0; j < 4; ++j) { h0[j] = f2h(v0[j]); h1[j] = f2h(v1[j]); }
  ((u16x4*)ph)[tid] = h0;
  ((u16x4*)ph)[tid + 256] = h1;
}

extern "C" void kernel_launch(void* const* d_in, const int* in_sizes, int n_in,
                              void* d_out, int out_size, void* d_ws, size_t ws_size,
                              hipStream_t stream) {
  const float* base  = (const float*)d_in[0];
  const float* x     = (const float*)d_in[1];
  const float* enc_t = (const float*)d_in[2];
  const float* enc_c = (const float*)d_in[3];
  const float* W     = (const float*)d_in[4];
  const float* bias  = (const float*)d_in[5];

  float* ctx  = (float*)d_out;                       // [B,C,T]
  float* attn = ctx + (long)B_ * C_ * T_;            // [B,T,S]

  const long NBTC = (long)B_ * T_ * C_;              // 8388608
  u16* ws   = (u16*)d_ws;
  u16* x_h  = ws;                   // fp16 [B,T,C]          [0, N)
  u16* et_h = ws + NBTC;            // fp16 [B,S,C]          [N, 2N)
  u16* pre  = ws + 2 * NBTC;        // fp16 pre_a->attn_h    [2N, 6N)  (= B*T*S)
  u16* ec_h = ws + 6 * NBTC;        // fp16 [B,C,S]          [6N, 7N)
  u16* w_h  = ws + 7 * NBTC;        // fp16 [C,C]
  u16* w_l  = w_h + (long)C_ * C_;  // fp16 [C,C] (exact residual)
  // total: (7*NBTC + 2*C*C)*2 B = 118,489,088 B — proven footprint

  // target fp16 hi/lo in d_out ctx region (2*NBTC u16 = exactly 32 MB, dead until GEMM3)
  u16* t_h = (u16*)d_out;
  u16* t_l = t_h + NBTC;

  // merged prep: transposes (x, enc_t) + enc_c convert + W split, one launch
  prep_kernel<<<dim3(64, 16, 25), 256, 0, stream>>>(
      x, enc_t, enc_c, W, x_h, et_h, ec_h, w_h, w_l);

  // GEMM1 (fp16 2-pass, W split exact): target + epilogue -> t_h/t_l
  gemm1_kernel<<<dim3(C_ / 128, T_ / 128, B_), 256, 0, stream>>>(
      x_h, w_h, w_l, base, bias, t_h, t_l);

  // GEMM2 (256x256 8-phase fp16, 16 k-tiles: Th.E + Tl.E) -> pre_a fp16 (ws)
  gemm8p_kernel<16, 8, 512, 4, 1><<<dim3(S_ / 256, T_ / 256, B_), 512, 0, stream>>>(
      t_h, t_l, et_h, pre,
      (long)T_ * C_, (long)S_ * C_, (long)T_ * S_, S_);

  // softmax: fp16 pre_a -> f32 attn (d_out) + fp16 attn in place
  softmax_kernel<<<B_ * T_, 256, 0, stream>>>(pre, attn);

  // GEMM3 (128x256 8-phase fp16, MF=2, 32 k-tiles, full occupancy):
  // ctx[c][t] = sum_s ec[c][s] * attn_h[t][s]
  gemm8p_kernel<32, 32, 2048, 2, 0><<<dim3(T_ / 256, C_ / 128, B_), 512, 0, stream>>>(
      ec_h, ec_h, pre, ctx,
      (long)C_ * S_, (long)T_ * S_, (long)C_ * T_, T_);

  (void)in_sizes; (void)n_in; (void)out_size; (void)ws_size;
}